// Round 12
// baseline (236.303 us; speedup 1.0000x reference)
//
#include <hip/hip_runtime.h>
#include <stdint.h>

// ---------------------------------------------------------------------------
// Single-head attention, B=4, S=2048, D=1024, fp32 in/out. bf16 MFMA pipeline.
//
//  0. mega_cvt2: fp32->bf16 Wq,Wk,Wv,Wo,query,key + bias copy (ONE dispatch)
//  1. [q;k] = [qf;kf] @ [Wq;Wk]^T + b    (z=2 batched)      [gemm256]
//  2. cvt value -> vf (overlays dead qf)
//  3. vT = Wv @ vf^T + bv                 [1024,8192]        [gemm8]
//  4. P  = q @ k^T / 32 (z=4)             [4,2048,2048]      [gemm256]
//  5. softmax rows of P in place
//  6. o  = P @ vT^T (z=4)                                    [gemm8]
//  7. out= o @ Wo^T + bo -> d_out (fp32)                     [gemm8]
//
// gemm256 = 8-phase 256x256 engine, R12 fix: ALL next-tile stages issue at
//   the TOP of each K-tile (ph0, before reads). R11 spread them across
//   phases ph0-ph3 while draining vmcnt(0) at tile top -> SB23 was only
//   ~600cy old at its drain (HBM lat ~900cy) = ~3000cy/tile stall. With
//   front-loaded stages the drain target is ~2800cy old -> free.
//   BM=BN=256 BK=64, 8 waves (2Mx4N), wave-tile 128x64, 2-dbuf 128KB,
//   4 phase-pairs of {reads | BAR | 16 MFMA | BAR}, setprio, T1 remap,
//   R5 swizzle (pre-swizzled source, 0 conflicts).
// gemm8 = R5/R10 engine verbatim (best for N=1024-ish shapes).
// ---------------------------------------------------------------------------

typedef __bf16  bf16x8 __attribute__((ext_vector_type(8)));
typedef float   f32x4  __attribute__((ext_vector_type(4)));
typedef unsigned int u32x4 __attribute__((ext_vector_type(4)));

__device__ __forceinline__ unsigned short bf16_rne(float f) {
  unsigned int u = __builtin_bit_cast(unsigned int, f);
  u += 0x7FFFu + ((u >> 16) & 1u);
  return (unsigned short)(u >> 16);
}
__device__ __forceinline__ unsigned int pack2(float a, float b) {
  return (unsigned int)bf16_rne(a) | ((unsigned int)bf16_rne(b) << 16);
}
__device__ __forceinline__ void async16(const unsigned short* g, unsigned short* l) {
  __builtin_amdgcn_global_load_lds(
      (const __attribute__((address_space(1))) unsigned int*)g,
      (__attribute__((address_space(3))) unsigned int*)l,
      16, 0, 0);
}

#define FENCE() asm volatile("" ::: "memory")
#define BAR()   __builtin_amdgcn_s_barrier()

#define MFMA_ __builtin_amdgcn_mfma_f32_16x16x32_bf16

// T1: XCD-chunked bijective remap (m204), work linearized x-fastest.
#define T1_REMAP() \
  const int nx   = gridDim.x, ny = gridDim.y; \
  const int nwg  = nx * ny * gridDim.z; \
  const int orig = (blockIdx.z * ny + blockIdx.y) * nx + blockIdx.x; \
  const int xcd  = orig & 7, loc = orig >> 3; \
  const int qq   = nwg >> 3, rr = nwg & 7; \
  const int w    = (xcd < rr ? xcd * (qq + 1) : rr * (qq + 1) + (xcd - rr) * qq) + loc; \
  const int bxi  = w % nx; \
  const int byi  = (w / nx) % ny; \
  const int bzi  = w / (nx * ny);

// ---------------------------------------------------------------------------
// gemm256: C[z][m][n] = scale * sum_k A[z][m][k]*B[z][n][k] (+bias)
// M % 256 == 0, N % 256 == 0, K % 64 == 0, K >= 128.
// ---------------------------------------------------------------------------
template<int OUT_F32>
__global__ __launch_bounds__(512, 1) void gemm256(
    const unsigned short* __restrict__ A, const unsigned short* __restrict__ B,
    void* __restrict__ Cp,
    int K, int lda, int ldb, int ldc,
    long sAz, long sBz, long sCz, long sBiasZ,
    float scale, const float* __restrict__ bias, int bias_mode)
{
  __shared__ unsigned short lds[2 * 32768];   // dbuf: A 16384 + B 16384 ushorts

  T1_REMAP();

  const int tid  = threadIdx.x;
  const int lane = tid & 63;
  const int wid  = tid >> 6;                  // 0..7
  const int bm   = byi * 256;
  const int bn   = bxi * 256;
  const long z   = bzi;

  const unsigned short* Az = A + z * sAz;
  const unsigned short* Bz = B + z * sBz;

  const int wm  = wid >> 2;                   // 0..1  (128 rows)
  const int wn  = wid & 3;                    // 0..3  (64 cols)
  const int al  = lane & 15;
  const int ah  = lane >> 4;
  const int al7 = lane & 7;

  const int swz = ((lane & 7) ^ ((lane >> 3) & 7)) << 3;
  const unsigned short* Apt = Az + (long)(bm + wid * 32 + (lane >> 3)) * lda + swz;
  const unsigned short* Bpt = Bz + (long)(bn + wid * 32 + (lane >> 3)) * ldb + swz;
  const long a8 = (long)lda * 8, b8 = (long)ldb * 8;

#define SALL(kt, stg) { \
    const unsigned short* pa_ = Apt + ((long)(kt) << 6); \
    const unsigned short* pb_ = Bpt + ((long)(kt) << 6); \
    async16(pa_,          (stg) + wid * 2048);        \
    async16(pa_ + a8,     (stg) + wid * 2048 + 512);  \
    async16(pa_ + 2 * a8, (stg) + wid * 2048 + 1024); \
    async16(pa_ + 3 * a8, (stg) + wid * 2048 + 1536); \
    async16(pb_,          (stg) + 16384 + wid * 2048);        \
    async16(pb_ + b8,     (stg) + 16384 + wid * 2048 + 512);  \
    async16(pb_ + 2 * b8, (stg) + 16384 + wid * 2048 + 1024); \
    async16(pb_ + 3 * b8, (stg) + 16384 + wid * 2048 + 1536); }

  // swizzled fragment reads: physical 16B unit = logical(kk*4+ah) ^ (row&7)
#define LDA2(v0, v1, mm) { const int r_ = (wm * 128 + (mm) * 16 + al) * 64; \
    v0 = *(const bf16x8*)&as[r_ + ((ah ^ al7) << 3)]; \
    v1 = *(const bf16x8*)&as[r_ + (((4 | ah) ^ al7) << 3)]; }
#define LDB2(v0, v1, nn) { const int r_ = (wn * 64 + (nn) * 16 + al) * 64; \
    v0 = *(const bf16x8*)&bs[r_ + ((ah ^ al7) << 3)]; \
    v1 = *(const bf16x8*)&bs[r_ + (((4 | ah) ^ al7) << 3)]; }
#define MM2(mi, ni, av0, av1, bv0, bv1) { \
    acc[mi][ni] = MFMA_(av0, bv0, acc[mi][ni], 0, 0, 0); \
    acc[mi][ni] = MFMA_(av1, bv1, acc[mi][ni], 0, 0, 0); }

  f32x4 acc[8][4] = {};
  const int nkt = K >> 6;

  // prologue: tile 0 into dbuf 0 (8 loads/wave in flight)
  SALL(0, lds);

  int cur = 0;
  for (int t = 0; t < nkt; ++t) {
    // tile t resident; its 8 loads were issued at the TOP of tile t-1
    // (~1 full K-tile of compute ago) -> this drain is ~free.
    asm volatile("s_waitcnt vmcnt(0)" ::: "memory");
    BAR(); FENCE();

    const unsigned short* as  = lds + cur * 32768;
    const unsigned short* bs  = as + 16384;
    unsigned short*       stg = lds + (cur ^ 1) * 32768;

    // R12: front-load ALL next-tile stages here (earliest possible issue)
    if (t + 1 < nkt) SALL(t + 1, stg);

    bf16x8 a0k0, a0k1, a1k0, a1k1, a2k0, a2k1, a3k0, a3k1;
    bf16x8 b0k0, b0k1, b1k0, b1k1, b2k0, b2k1, b3k0, b3k1;

    // ---- ph0: A m0-3 (8 reads) + B n01 (4)
    LDA2(a0k0, a0k1, 0); LDA2(a1k0, a1k1, 1); LDA2(a2k0, a2k1, 2); LDA2(a3k0, a3k1, 3);
    LDB2(b0k0, b0k1, 0); LDB2(b1k0, b1k1, 1);
    FENCE(); BAR();
    __builtin_amdgcn_s_setprio(1);
    MM2(0,0, a0k0,a0k1, b0k0,b0k1); MM2(1,0, a1k0,a1k1, b0k0,b0k1);
    MM2(2,0, a2k0,a2k1, b0k0,b0k1); MM2(3,0, a3k0,a3k1, b0k0,b0k1);
    MM2(0,1, a0k0,a0k1, b1k0,b1k1); MM2(1,1, a1k0,a1k1, b1k0,b1k1);
    MM2(2,1, a2k0,a2k1, b1k0,b1k1); MM2(3,1, a3k0,a3k1, b1k0,b1k1);
    __builtin_amdgcn_s_setprio(0);
    BAR(); FENCE();

    // ---- ph1: B n23 (4 reads)
    LDB2(b2k0, b2k1, 2); LDB2(b3k0, b3k1, 3);
    FENCE(); BAR();
    __builtin_amdgcn_s_setprio(1);
    MM2(0,2, a0k0,a0k1, b2k0,b2k1); MM2(1,2, a1k0,a1k1, b2k0,b2k1);
    MM2(2,2, a2k0,a2k1, b2k0,b2k1); MM2(3,2, a3k0,a3k1, b2k0,b2k1);
    MM2(0,3, a0k0,a0k1, b3k0,b3k1); MM2(1,3, a1k0,a1k1, b3k0,b3k1);
    MM2(2,3, a2k0,a2k1, b3k0,b3k1); MM2(3,3, a3k0,a3k1, b3k0,b3k1);
    __builtin_amdgcn_s_setprio(0);
    BAR(); FENCE();

    // ---- ph2: A m4-7 (8 reads, recycle registers)
    LDA2(a0k0, a0k1, 4); LDA2(a1k0, a1k1, 5); LDA2(a2k0, a2k1, 6); LDA2(a3k0, a3k1, 7);
    FENCE(); BAR();
    __builtin_amdgcn_s_setprio(1);
    MM2(4,0, a0k0,a0k1, b0k0,b0k1); MM2(5,0, a1k0,a1k1, b0k0,b0k1);
    MM2(6,0, a2k0,a2k1, b0k0,b0k1); MM2(7,0, a3k0,a3k1, b0k0,b0k1);
    MM2(4,1, a0k0,a0k1, b1k0,b1k1); MM2(5,1, a1k0,a1k1, b1k0,b1k1);
    MM2(6,1, a2k0,a2k1, b1k0,b1k1); MM2(7,1, a3k0,a3k1, b1k0,b1k1);
    __builtin_amdgcn_s_setprio(0);
    BAR(); FENCE();

    // ---- ph3: no reads
    __builtin_amdgcn_s_setprio(1);
    MM2(4,2, a0k0,a0k1, b2k0,b2k1); MM2(5,2, a1k0,a1k1, b2k0,b2k1);
    MM2(6,2, a2k0,a2k1, b2k0,b2k1); MM2(7,2, a3k0,a3k1, b2k0,b2k1);
    MM2(4,3, a0k0,a0k1, b3k0,b3k1); MM2(5,3, a1k0,a1k1, b3k0,b3k1);
    MM2(6,3, a2k0,a2k1, b3k0,b3k1); MM2(7,3, a3k0,a3k1, b3k0,b3k1);
    __builtin_amdgcn_s_setprio(0);

    cur ^= 1;
  }

  // Epilogue. C/D layout: col = lane&15, row = (lane>>4)*4 + j
  #pragma unroll
  for (int m = 0; m < 8; ++m) {
    #pragma unroll
    for (int n = 0; n < 4; ++n) {
      #pragma unroll
      for (int j = 0; j < 4; ++j) {
        const int grow = bm + wm * 128 + m * 16 + ah * 4 + j;
        const int gcol = bn + wn * 64 + n * 16 + al;
        float v = acc[m][n][j] * scale;
        if (bias_mode == 1)      v += bias[z * sBiasZ + gcol];
        else if (bias_mode == 2) v += bias[z * sBiasZ + grow];
        const long idx = z * sCz + (long)grow * ldc + gcol;
        if (OUT_F32) ((float*)Cp)[idx] = v;
        else         ((unsigned short*)Cp)[idx] = bf16_rne(v);
      }
    }
  }
}

// ---------------------------------------------------------------------------
// gemm8 = R10 verbatim. M % 256 == 0, N % 128 == 0, K % 64 == 0, K >= 192.
// ---------------------------------------------------------------------------
template<int OUT_F32>
__global__ __launch_bounds__(512, 2) void gemm8(
    const unsigned short* __restrict__ A, const unsigned short* __restrict__ B,
    void* __restrict__ Cp,
    int K, int lda, int ldb, int ldc,
    long sAz, long sBz, long sCz, long sBiasZ,
    float scale, const float* __restrict__ bias, int bias_mode)
{
  __shared__ unsigned short lds[3 * 24576];   // per buf: A 16384 + B 8192 ushorts

  T1_REMAP();

  const int tid  = threadIdx.x;
  const int lane = tid & 63;
  const int wid  = tid >> 6;                  // 0..7
  const int bm   = byi * 256;
  const int bn   = bxi * 128;
  const long z   = bzi;

  const unsigned short* Az = A + z * sAz;
  const unsigned short* Bz = B + z * sBz;

  const int wr  = (wid >> 1) * 64;
  const int wc  = (wid & 1)  * 64;
  const int al  = lane & 15;
  const int ah  = lane >> 4;
  const int al7 = lane & 7;

  const int swz = ((lane & 7) ^ ((lane >> 3) & 7)) << 3;
  const unsigned short* Apt = Az + (long)(bm + wid * 32 + (lane >> 3)) * lda + swz;
  const unsigned short* Bpt = Bz + (long)(bn + wid * 16 + (lane >> 3)) * ldb + swz;
  const long a8 = (long)lda * 8, b8 = (long)ldb * 8;

  f32x4 acc[4][4] = {};
  const int nkt = K >> 6;

#define STAGE_A(kt, stg) { const unsigned short* a_ = Apt + ((long)(kt) << 6); \
    async16(a_,          (stg) + wid * 2048);        \
    async16(a_ + a8,     (stg) + wid * 2048 + 512);  \
    async16(a_ + 2 * a8, (stg) + wid * 2048 + 1024); \
    async16(a_ + 3 * a8, (stg) + wid * 2048 + 1536); }
#define STAGE_B(kt, stg) { const unsigned short* b_ = Bpt + ((long)(kt) << 6); \
    async16(b_,      (stg) + 16384 + wid * 1024); \
    async16(b_ + b8, (stg) + 16384 + wid * 1024 + 512); }

#define LDA_(m) { const int r_ = (wr + (m) * 16 + al) * 64; \
    af##m##0 = *(const bf16x8*)&as[r_ + ((ah ^ al7) << 3)]; \
    af##m##1 = *(const bf16x8*)&as[r_ + (((4 | ah) ^ al7) << 3)]; }
#define LDB_(n) { const int r_ = (wc + (n) * 16 + al) * 64; \
    bf##n##0 = *(const bf16x8*)&bs[r_ + ((ah ^ al7) << 3)]; \
    bf##n##1 = *(const bf16x8*)&bs[r_ + (((4 | ah) ^ al7) << 3)]; }
#define MM(m, n) { \
    acc[m][n] = MFMA_(af##m##0, bf##n##0, acc[m][n], 0, 0, 0); \
    acc[m][n] = MFMA_(af##m##1, bf##n##1, acc[m][n], 0, 0, 0); }

  STAGE_A(0, lds); STAGE_B(0, lds);
  STAGE_A(1, lds + 24576); STAGE_B(1, lds + 24576);

  int cur = 0;
  for (int t = 0; t < nkt; ++t) {
    const int stb  = (cur >= 1) ? cur - 1 : cur + 2;
    const bool more = (t + 2) < nkt;

    if (t + 1 < nkt) asm volatile("s_waitcnt vmcnt(6)" ::: "memory");
    else             asm volatile("s_waitcnt vmcnt(0)" ::: "memory");
    BAR(); FENCE();

    const unsigned short* as  = lds + cur * 24576;
    const unsigned short* bs  = as + 16384;
    unsigned short*       stg = lds + stb * 24576;

    bf16x8 af00, af01, af10, af11, af20, af21, af30, af31;
    bf16x8 bf00, bf01, bf10, bf11, bf20, bf21, bf30, bf31;

    LDA_(0); LDA_(1); LDA_(2); LDA_(3);
    LDB_(0); LDB_(1);
    if (more) STAGE_A(t + 2, stg);
    FENCE(); BAR();
    __builtin_amdgcn_s_setprio(1);
    MM(0,0); MM(1,0); MM(2,0); MM(3,0);
    MM(0,1); MM(1,1); MM(2,1); MM(3,1);
    __builtin_amdgcn_s_setprio(0);
    BAR(); FENCE();

    LDB_(2); LDB_(3);
    if (more) STAGE_B(t + 2, stg);
    FENCE(); BAR();
    __builtin_amdgcn_s_setprio(1);
    MM(0,2); MM(1,2); MM(2,2); MM(3,2);
    MM(0,3); MM(1,3); MM(2,3); MM(3,3);
    __builtin_amdgcn_s_setprio(0);
    BAR(); FENCE();

    cur = (cur == 2) ? 0 : cur + 1;
  }

  #pragma unroll
  for (int m = 0; m < 4; ++m) {
    #pragma unroll
    for (int n = 0; n < 4; ++n) {
      #pragma unroll
      for (int j = 0; j < 4; ++j) {
        const int grow = bm + wr + m * 16 + ah * 4 + j;
        const int gcol = bn + wc + n * 16 + al;
        float v = acc[m][n][j] * scale;
        if (bias_mode == 1)      v += bias[z * sBiasZ + gcol];
        else if (bias_mode == 2) v += bias[z * sBiasZ + grow];
        const long idx = z * sCz + (long)grow * ldc + gcol;
        if (OUT_F32) ((float*)Cp)[idx] = v;
        else         ((unsigned short*)Cp)[idx] = bf16_rne(v);
      }
    }
  }
}

// ---------------------------------------------------------------------------
__device__ __forceinline__ void cvt8(const float* in, unsigned short* out, long i) {
  f32x4 a = *(const f32x4*)(in + i * 8);
  f32x4 b = *(const f32x4*)(in + i * 8 + 4);
  u32x4 w;
  w[0] = pack2(a[0], a[1]); w[1] = pack2(a[2], a[3]);
  w[2] = pack2(b[0], b[1]); w[3] = pack2(b[2], b[3]);
  *(u32x4*)(out + i * 8) = w;
}

__global__ __launch_bounds__(256) void mega_cvt2(
    const float* __restrict__ wq, const float* __restrict__ wk,
    const float* __restrict__ wv, const float* __restrict__ wo,
    const float* __restrict__ query, const float* __restrict__ key_,
    const float* __restrict__ bq, const float* __restrict__ bk,
    unsigned short* __restrict__ Wb, unsigned short* __restrict__ qf,
    unsigned short* __restrict__ kf, float* __restrict__ bqk)
{
  const int b = blockIdx.x;
  if (b < 2048) {
    const long i = (long)(b & 511) * 256 + threadIdx.x;
    if (b < 512)        cvt8(wq, Wb,            i);
    else if (b < 1024)  cvt8(wk, Wb + 1048576,  i);
    else if (b < 1536)  cvt8(wv, Wb + 2097152,  i);
    else                cvt8(wo, Wb + 3145728,  i);
  } else if (b < 6144) {
    cvt8(query, qf, (long)(b - 2048) * 256 + threadIdx.x);
  } else if (b < 10240) {
    cvt8(key_,  kf, (long)(b - 6144) * 256 + threadIdx.x);
  } else {
    const int t = (b - 10240) * 256 + threadIdx.x;
    if (t < 1024) bqk[t] = bq[t];
    else          bqk[t] = bk[t - 1024];
  }
}

__global__ __launch_bounds__(256) void cvt_f32_bf16(
    const float* __restrict__ in, unsigned short* __restrict__ out, int n8)
{
  const int i = blockIdx.x * 256 + threadIdx.x;
  if (i >= n8) return;
  cvt8(in, out, i);
}

// ---------------------------------------------------------------------------
__global__ __launch_bounds__(256) void softmax_inplace(unsigned short* __restrict__ P) {
  const long row = blockIdx.x;
  unsigned short* pr = P + row * 2048;
  const int tid = threadIdx.x;

  u32x4 raw = *(const u32x4*)&pr[tid * 8];
  float s[8];
  #pragma unroll
  for (int i = 0; i < 4; ++i) {
    unsigned int u = raw[i];
    s[2 * i]     = __builtin_bit_cast(float, u << 16);
    s[2 * i + 1] = __builtin_bit_cast(float, u & 0xFFFF0000u);
  }
  float m = s[0];
  #pragma unroll
  for (int i = 1; i < 8; ++i) m = fmaxf(m, s[i]);
  #pragma unroll
  for (int off = 32; off >= 1; off >>= 1) m = fmaxf(m, __shfl_xor(m, off));

  __shared__ float redm[4], reds[4];
  const int wid = tid >> 6, lane = tid & 63;
  if (lane == 0) redm[wid] = m;
  __syncthreads();
  m = fmaxf(fmaxf(redm[0], redm[1]), fmaxf(redm[2], redm[3]));

  float e[8], sum = 0.f;
  #pragma unroll
  for (int i = 0; i < 8; ++i) { e[i] = __expf(s[i] - m); sum += e[i]; }
  #pragma unroll
  for (int off = 32; off >= 1; off >>= 1) sum += __shfl_xor(sum, off);
  if (lane == 0) reds[wid] = sum;
  __syncthreads();
  sum = reds[0] + reds[1] + reds[2] + reds[3];
  const float inv = 1.0f / sum;

  u32x4 outw;
  #pragma unroll
  for (int i = 0; i < 4; ++i) outw[i] = pack2(e[2 * i] * inv, e[2 * i + 1] * inv);
  *(u32x4*)&pr[tid * 8] = outw;
}

// ---------------------------------------------------------------------------
extern "C" void kernel_launch(void* const* d_in, const int* in_sizes, int n_in,
                              void* d_out, int out_size, void* d_ws, size_t ws_size,
                              hipStream_t stream) {
  const float* query = (const float*)d_in[0];
  const float* key_  = (const float*)d_in[1];
  const float* value = (const float*)d_in[2];
  const float* Wq    = (const float*)d_in[3];
  const float* bq    = (const float*)d_in[4];
  const float* Wk    = (const float*)d_in[5];
  const float* bk    = (const float*)d_in[6];
  const float* Wv    = (const float*)d_in[7];
  const float* bv    = (const float*)d_in[8];
  const float* Wo    = (const float*)d_in[9];
  const float* bo    = (const float*)d_in[10];

  unsigned short* ws = (unsigned short*)d_ws;
  unsigned short* qf = ws;                        // [8192][1024] -> vf -> P lower
  unsigned short* kf = ws + 8388608;              // [8192][1024] -> P upper
  unsigned short* vf = ws;                        // overlays dead qf
  unsigned short* P  = ws;                        // [4][2048][2048]
  unsigned short* q  = ws + 16777216;             // [2][8.4M] q,k -> later o
  unsigned short* vT = ws + 33554432;             // [1024][8192]
  unsigned short* Wb = ws + 41943040;             // 4 x [1024][1024] bf16
  float*          bqk= (float*)(ws + 46137344);   // [2][1024] fp32
  unsigned short* o  = q;                         // overlays dead q

  const dim3 blk(256), blk8(512);

  // 0: all prologue conversions + bias copy in ONE dispatch
  mega_cvt2<<<dim3(10248), blk, 0, stream>>>(Wq, Wk, Wv, Wo, query, key_,
                                             bq, bk, Wb, qf, kf, bqk);

  // 1: [q;k] projections, z=2. M=8192, N=1024, K=1024. 256 blocks, 1 round.
  gemm256<0><<<dim3(4, 32, 2), blk8, 0, stream>>>(qf, Wb, q,
      1024, 1024, 1024, 1024, 8388608L, 1048576L, 8388608L, 1024L, 1.0f, bqk, 1);

  // 2: convert value (into region freed by qf)
  cvt_f32_bf16<<<dim3(4096), blk, 0, stream>>>(value, vf, 1048576);

  // 3: vT = Wv @ vf^T + bv. M=1024, N=8192, K=1024, bias per-row. 256 blocks.
  gemm8<0><<<dim3(64, 4, 1), blk8, 0, stream>>>(Wb + 2097152, vf, vT,
      1024, 1024, 1024, 8192, 0L, 0L, 0L, 0L, 1.0f, bv, 2);

  // 4: P = q @ k^T / 32, z=4. M=N=2048, K=1024. 256 blocks, 1 round.
  gemm256<0><<<dim3(8, 8, 4), blk8, 0, stream>>>(q, q + 8388608, P,
      1024, 1024, 1024, 2048, 2097152L, 2097152L, 4194304L, 0L, 0.03125f, nullptr, 0);

  // 5: softmax rows in place (8192 rows x 2048)
  softmax_inplace<<<dim3(8192), blk, 0, stream>>>(P);

  // 6: o = P @ vT^T, z=4. M=2048, N=1024, K=2048. 256 blocks.
  gemm8<0><<<dim3(8, 8, 4), blk8, 0, stream>>>(P, vT, o,
      2048, 2048, 8192, 1024, 4194304L, 2048L, 2097152L, 0L, 1.0f, nullptr, 0);

  // 7: out = o @ Wo^T + bo (fp32 out). M=8192, N=1024, K=1024. 256 blocks.
  gemm8<1><<<dim3(8, 32, 1), blk8, 0, stream>>>(o, Wb + 3145728, d_out,
      1024, 1024, 1024, 1024, 0L, 0L, 0L, 0L, 1.0f, bo, 1);
}

// Round 13
// 233.672 us; speedup vs baseline: 1.0113x; 1.0113x over previous
//
#include <hip/hip_runtime.h>
#include <stdint.h>

// ---------------------------------------------------------------------------
// Single-head attention, B=4, S=2048, D=1024, fp32 in/out. bf16 MFMA pipeline.
//
//  0. mega_cvt3: fp32->bf16 Wq,Wk,Wv,Wo,query,key(,value if ws allows) + bias
//  1. [q;k] = [qf;kf] @ [Wq;Wk]^T + b    (z=2 batched)      [gemm256]
//  2. (fallback only) cvt value -> vf
//  3. vT = Wv @ vf^T + bv                 [1024,8192]        [gemm8]
//  4. P  = q @ k^T / 32 (z=4)             [4,2048,2048]      [gemm256]
//  5. softmax rows of P in place
//  6. o  = P @ vT^T (z=4)                                    [gemm8]
//  7. out= o @ Wo^T + bo -> d_out (fp32)                     [gemm8]
//
// gemm256 = R11 exact (best measured: 57.0us/dispatch, 235.0us total):
//   BM=BN=256 BK=64, 8 waves (2Mx4N), wave-tile 128x64, 2-dbuf 128KB,
//   4 phase-pairs {reads | BAR | 16 MFMA | BAR}, next-tile stages spread
//   one pair per phase, vmcnt(0) at tile top (measured free), setprio,
//   T1 XCD remap, R5 swizzle (pre-swizzled source, 0 conflicts).
//   NOTE R2-R12 evidence: per-K-tile ~8550cy with ~3000cy structure-invariant
//   dead time across 9 schedule variants -> engine is at local minimum.
// gemm8 = R5/R10 engine verbatim (best for N=1024-ish shapes).
// ---------------------------------------------------------------------------

typedef __bf16  bf16x8 __attribute__((ext_vector_type(8)));
typedef float   f32x4  __attribute__((ext_vector_type(4)));
typedef unsigned int u32x4 __attribute__((ext_vector_type(4)));

__device__ __forceinline__ unsigned short bf16_rne(float f) {
  unsigned int u = __builtin_bit_cast(unsigned int, f);
  u += 0x7FFFu + ((u >> 16) & 1u);
  return (unsigned short)(u >> 16);
}
__device__ __forceinline__ unsigned int pack2(float a, float b) {
  return (unsigned int)bf16_rne(a) | ((unsigned int)bf16_rne(b) << 16);
}
__device__ __forceinline__ void async16(const unsigned short* g, unsigned short* l) {
  __builtin_amdgcn_global_load_lds(
      (const __attribute__((address_space(1))) unsigned int*)g,
      (__attribute__((address_space(3))) unsigned int*)l,
      16, 0, 0);
}

#define FENCE() asm volatile("" ::: "memory")
#define BAR()   __builtin_amdgcn_s_barrier()

#define MFMA_ __builtin_amdgcn_mfma_f32_16x16x32_bf16

// T1: XCD-chunked bijective remap (m204), work linearized x-fastest.
#define T1_REMAP() \
  const int nx   = gridDim.x, ny = gridDim.y; \
  const int nwg  = nx * ny * gridDim.z; \
  const int orig = (blockIdx.z * ny + blockIdx.y) * nx + blockIdx.x; \
  const int xcd  = orig & 7, loc = orig >> 3; \
  const int qq   = nwg >> 3, rr = nwg & 7; \
  const int w    = (xcd < rr ? xcd * (qq + 1) : rr * (qq + 1) + (xcd - rr) * qq) + loc; \
  const int bxi  = w % nx; \
  const int byi  = (w / nx) % ny; \
  const int bzi  = w / (nx * ny);

// ---------------------------------------------------------------------------
// gemm256: C[z][m][n] = scale * sum_k A[z][m][k]*B[z][n][k] (+bias)
// M % 256 == 0, N % 256 == 0, K % 64 == 0, K >= 128.
// ---------------------------------------------------------------------------
template<int OUT_F32>
__global__ __launch_bounds__(512, 1) void gemm256(
    const unsigned short* __restrict__ A, const unsigned short* __restrict__ B,
    void* __restrict__ Cp,
    int K, int lda, int ldb, int ldc,
    long sAz, long sBz, long sCz, long sBiasZ,
    float scale, const float* __restrict__ bias, int bias_mode)
{
  __shared__ unsigned short lds[2 * 32768];   // dbuf: A 16384 + B 16384 ushorts

  T1_REMAP();

  const int tid  = threadIdx.x;
  const int lane = tid & 63;
  const int wid  = tid >> 6;                  // 0..7
  const int bm   = byi * 256;
  const int bn   = bxi * 256;
  const long z   = bzi;

  const unsigned short* Az = A + z * sAz;
  const unsigned short* Bz = B + z * sBz;

  const int wm  = wid >> 2;                   // 0..1  (128 rows)
  const int wn  = wid & 3;                    // 0..3  (64 cols)
  const int al  = lane & 15;
  const int ah  = lane >> 4;
  const int al7 = lane & 7;

  const int swz = ((lane & 7) ^ ((lane >> 3) & 7)) << 3;
  const unsigned short* Apt = Az + (long)(bm + wid * 32 + (lane >> 3)) * lda + swz;
  const unsigned short* Bpt = Bz + (long)(bn + wid * 32 + (lane >> 3)) * ldb + swz;
  const long a8 = (long)lda * 8, b8 = (long)ldb * 8;

#define SA01(kt, stg) { const unsigned short* p_ = Apt + ((long)(kt) << 6); \
    async16(p_,      (stg) + wid * 2048);       \
    async16(p_ + a8, (stg) + wid * 2048 + 512); }
#define SA23(kt, stg) { const unsigned short* p_ = Apt + ((long)(kt) << 6) + 2 * a8; \
    async16(p_,      (stg) + wid * 2048 + 1024); \
    async16(p_ + a8, (stg) + wid * 2048 + 1536); }
#define SB01(kt, stg) { const unsigned short* p_ = Bpt + ((long)(kt) << 6); \
    async16(p_,      (stg) + 16384 + wid * 2048);       \
    async16(p_ + b8, (stg) + 16384 + wid * 2048 + 512); }
#define SB23(kt, stg) { const unsigned short* p_ = Bpt + ((long)(kt) << 6) + 2 * b8; \
    async16(p_,      (stg) + 16384 + wid * 2048 + 1024); \
    async16(p_ + b8, (stg) + 16384 + wid * 2048 + 1536); }

  // swizzled fragment reads: physical 16B unit = logical(kk*4+ah) ^ (row&7)
#define LDA2(v0, v1, mm) { const int r_ = (wm * 128 + (mm) * 16 + al) * 64; \
    v0 = *(const bf16x8*)&as[r_ + ((ah ^ al7) << 3)]; \
    v1 = *(const bf16x8*)&as[r_ + (((4 | ah) ^ al7) << 3)]; }
#define LDB2(v0, v1, nn) { const int r_ = (wn * 64 + (nn) * 16 + al) * 64; \
    v0 = *(const bf16x8*)&bs[r_ + ((ah ^ al7) << 3)]; \
    v1 = *(const bf16x8*)&bs[r_ + (((4 | ah) ^ al7) << 3)]; }
#define MM2(mi, ni, av0, av1, bv0, bv1) { \
    acc[mi][ni] = MFMA_(av0, bv0, acc[mi][ni], 0, 0, 0); \
    acc[mi][ni] = MFMA_(av1, bv1, acc[mi][ni], 0, 0, 0); }

  f32x4 acc[8][4] = {};
  const int nkt = K >> 6;

  // prologue: tile 0 into dbuf 0 (8 loads/wave in flight)
  SA01(0, lds); SA23(0, lds); SB01(0, lds); SB23(0, lds);

  int cur = 0;
  for (int t = 0; t < nkt; ++t) {
    asm volatile("s_waitcnt vmcnt(0)" ::: "memory");
    BAR(); FENCE();

    const unsigned short* as  = lds + cur * 32768;
    const unsigned short* bs  = as + 16384;
    unsigned short*       stg = lds + (cur ^ 1) * 32768;
    const bool more = (t + 1) < nkt;

    bf16x8 a0k0, a0k1, a1k0, a1k1, a2k0, a2k1, a3k0, a3k1;
    bf16x8 b0k0, b0k1, b1k0, b1k1, b2k0, b2k1, b3k0, b3k1;

    // ---- ph0: A m0-3 (8 reads) + B n01 (4); stage A01(t+1)
    LDA2(a0k0, a0k1, 0); LDA2(a1k0, a1k1, 1); LDA2(a2k0, a2k1, 2); LDA2(a3k0, a3k1, 3);
    LDB2(b0k0, b0k1, 0); LDB2(b1k0, b1k1, 1);
    if (more) SA01(t + 1, stg);
    FENCE(); BAR();
    __builtin_amdgcn_s_setprio(1);
    MM2(0,0, a0k0,a0k1, b0k0,b0k1); MM2(1,0, a1k0,a1k1, b0k0,b0k1);
    MM2(2,0, a2k0,a2k1, b0k0,b0k1); MM2(3,0, a3k0,a3k1, b0k0,b0k1);
    MM2(0,1, a0k0,a0k1, b1k0,b1k1); MM2(1,1, a1k0,a1k1, b1k0,b1k1);
    MM2(2,1, a2k0,a2k1, b1k0,b1k1); MM2(3,1, a3k0,a3k1, b1k0,b1k1);
    __builtin_amdgcn_s_setprio(0);
    BAR(); FENCE();

    // ---- ph1: B n23 (4 reads); stage A23(t+1)
    LDB2(b2k0, b2k1, 2); LDB2(b3k0, b3k1, 3);
    if (more) SA23(t + 1, stg);
    FENCE(); BAR();
    __builtin_amdgcn_s_setprio(1);
    MM2(0,2, a0k0,a0k1, b2k0,b2k1); MM2(1,2, a1k0,a1k1, b2k0,b2k1);
    MM2(2,2, a2k0,a2k1, b2k0,b2k1); MM2(3,2, a3k0,a3k1, b2k0,b2k1);
    MM2(0,3, a0k0,a0k1, b3k0,b3k1); MM2(1,3, a1k0,a1k1, b3k0,b3k1);
    MM2(2,3, a2k0,a2k1, b3k0,b3k1); MM2(3,3, a3k0,a3k1, b3k0,b3k1);
    __builtin_amdgcn_s_setprio(0);
    BAR(); FENCE();

    // ---- ph2: A m4-7 (8 reads, recycle registers); stage B01(t+1)
    LDA2(a0k0, a0k1, 4); LDA2(a1k0, a1k1, 5); LDA2(a2k0, a2k1, 6); LDA2(a3k0, a3k1, 7);
    if (more) SB01(t + 1, stg);
    FENCE(); BAR();
    __builtin_amdgcn_s_setprio(1);
    MM2(4,0, a0k0,a0k1, b0k0,b0k1); MM2(5,0, a1k0,a1k1, b0k0,b0k1);
    MM2(6,0, a2k0,a2k1, b0k0,b0k1); MM2(7,0, a3k0,a3k1, b0k0,b0k1);
    MM2(4,1, a0k0,a0k1, b1k0,b1k1); MM2(5,1, a1k0,a1k1, b1k0,b1k1);
    MM2(6,1, a2k0,a2k1, b1k0,b1k1); MM2(7,1, a3k0,a3k1, b1k0,b1k1);
    __builtin_amdgcn_s_setprio(0);
    BAR(); FENCE();

    // ---- ph3: no reads; stage B23(t+1)
    if (more) SB23(t + 1, stg);
    FENCE(); BAR();
    __builtin_amdgcn_s_setprio(1);
    MM2(4,2, a0k0,a0k1, b2k0,b2k1); MM2(5,2, a1k0,a1k1, b2k0,b2k1);
    MM2(6,2, a2k0,a2k1, b2k0,b2k1); MM2(7,2, a3k0,a3k1, b2k0,b2k1);
    MM2(4,3, a0k0,a0k1, b3k0,b3k1); MM2(5,3, a1k0,a1k1, b3k0,b3k1);
    MM2(6,3, a2k0,a2k1, b3k0,b3k1); MM2(7,3, a3k0,a3k1, b3k0,b3k1);
    __builtin_amdgcn_s_setprio(0);

    cur ^= 1;
  }

  // Epilogue. C/D layout: col = lane&15, row = (lane>>4)*4 + j
  #pragma unroll
  for (int m = 0; m < 8; ++m) {
    #pragma unroll
    for (int n = 0; n < 4; ++n) {
      #pragma unroll
      for (int j = 0; j < 4; ++j) {
        const int grow = bm + wm * 128 + m * 16 + ah * 4 + j;
        const int gcol = bn + wn * 64 + n * 16 + al;
        float v = acc[m][n][j] * scale;
        if (bias_mode == 1)      v += bias[z * sBiasZ + gcol];
        else if (bias_mode == 2) v += bias[z * sBiasZ + grow];
        const long idx = z * sCz + (long)grow * ldc + gcol;
        if (OUT_F32) ((float*)Cp)[idx] = v;
        else         ((unsigned short*)Cp)[idx] = bf16_rne(v);
      }
    }
  }
}

// ---------------------------------------------------------------------------
// gemm8 = R10 verbatim. M % 256 == 0, N % 128 == 0, K % 64 == 0, K >= 192.
// ---------------------------------------------------------------------------
template<int OUT_F32>
__global__ __launch_bounds__(512, 2) void gemm8(
    const unsigned short* __restrict__ A, const unsigned short* __restrict__ B,
    void* __restrict__ Cp,
    int K, int lda, int ldb, int ldc,
    long sAz, long sBz, long sCz, long sBiasZ,
    float scale, const float* __restrict__ bias, int bias_mode)
{
  __shared__ unsigned short lds[3 * 24576];   // per buf: A 16384 + B 8192 ushorts

  T1_REMAP();

  const int tid  = threadIdx.x;
  const int lane = tid & 63;
  const int wid  = tid >> 6;                  // 0..7
  const int bm   = byi * 256;
  const int bn   = bxi * 128;
  const long z   = bzi;

  const unsigned short* Az = A + z * sAz;
  const unsigned short* Bz = B + z * sBz;

  const int wr  = (wid >> 1) * 64;
  const int wc  = (wid & 1)  * 64;
  const int al  = lane & 15;
  const int ah  = lane >> 4;
  const int al7 = lane & 7;

  const int swz = ((lane & 7) ^ ((lane >> 3) & 7)) << 3;
  const unsigned short* Apt = Az + (long)(bm + wid * 32 + (lane >> 3)) * lda + swz;
  const unsigned short* Bpt = Bz + (long)(bn + wid * 16 + (lane >> 3)) * ldb + swz;
  const long a8 = (long)lda * 8, b8 = (long)ldb * 8;

  f32x4 acc[4][4] = {};
  const int nkt = K >> 6;

#define STAGE_A(kt, stg) { const unsigned short* a_ = Apt + ((long)(kt) << 6); \
    async16(a_,          (stg) + wid * 2048);        \
    async16(a_ + a8,     (stg) + wid * 2048 + 512);  \
    async16(a_ + 2 * a8, (stg) + wid * 2048 + 1024); \
    async16(a_ + 3 * a8, (stg) + wid * 2048 + 1536); }
#define STAGE_B(kt, stg) { const unsigned short* b_ = Bpt + ((long)(kt) << 6); \
    async16(b_,      (stg) + 16384 + wid * 1024); \
    async16(b_ + b8, (stg) + 16384 + wid * 1024 + 512); }

#define LDA_(m) { const int r_ = (wr + (m) * 16 + al) * 64; \
    af##m##0 = *(const bf16x8*)&as[r_ + ((ah ^ al7) << 3)]; \
    af##m##1 = *(const bf16x8*)&as[r_ + (((4 | ah) ^ al7) << 3)]; }
#define LDB_(n) { const int r_ = (wc + (n) * 16 + al) * 64; \
    bf##n##0 = *(const bf16x8*)&bs[r_ + ((ah ^ al7) << 3)]; \
    bf##n##1 = *(const bf16x8*)&bs[r_ + (((4 | ah) ^ al7) << 3)]; }
#define MM(m, n) { \
    acc[m][n] = MFMA_(af##m##0, bf##n##0, acc[m][n], 0, 0, 0); \
    acc[m][n] = MFMA_(af##m##1, bf##n##1, acc[m][n], 0, 0, 0); }

  STAGE_A(0, lds); STAGE_B(0, lds);
  STAGE_A(1, lds + 24576); STAGE_B(1, lds + 24576);

  int cur = 0;
  for (int t = 0; t < nkt; ++t) {
    const int stb  = (cur >= 1) ? cur - 1 : cur + 2;
    const bool more = (t + 2) < nkt;

    if (t + 1 < nkt) asm volatile("s_waitcnt vmcnt(6)" ::: "memory");
    else             asm volatile("s_waitcnt vmcnt(0)" ::: "memory");
    BAR(); FENCE();

    const unsigned short* as  = lds + cur * 24576;
    const unsigned short* bs  = as + 16384;
    unsigned short*       stg = lds + stb * 24576;

    bf16x8 af00, af01, af10, af11, af20, af21, af30, af31;
    bf16x8 bf00, bf01, bf10, bf11, bf20, bf21, bf30, bf31;

    LDA_(0); LDA_(1); LDA_(2); LDA_(3);
    LDB_(0); LDB_(1);
    if (more) STAGE_A(t + 2, stg);
    FENCE(); BAR();
    __builtin_amdgcn_s_setprio(1);
    MM(0,0); MM(1,0); MM(2,0); MM(3,0);
    MM(0,1); MM(1,1); MM(2,1); MM(3,1);
    __builtin_amdgcn_s_setprio(0);
    BAR(); FENCE();

    LDB_(2); LDB_(3);
    if (more) STAGE_B(t + 2, stg);
    FENCE(); BAR();
    __builtin_amdgcn_s_setprio(1);
    MM(0,2); MM(1,2); MM(2,2); MM(3,2);
    MM(0,3); MM(1,3); MM(2,3); MM(3,3);
    __builtin_amdgcn_s_setprio(0);
    BAR(); FENCE();

    cur = (cur == 2) ? 0 : cur + 1;
  }

  #pragma unroll
  for (int m = 0; m < 4; ++m) {
    #pragma unroll
    for (int n = 0; n < 4; ++n) {
      #pragma unroll
      for (int j = 0; j < 4; ++j) {
        const int grow = bm + wr + m * 16 + ah * 4 + j;
        const int gcol = bn + wc + n * 16 + al;
        float v = acc[m][n][j] * scale;
        if (bias_mode == 1)      v += bias[z * sBiasZ + gcol];
        else if (bias_mode == 2) v += bias[z * sBiasZ + grow];
        const long idx = z * sCz + (long)grow * ldc + gcol;
        if (OUT_F32) ((float*)Cp)[idx] = v;
        else         ((unsigned short*)Cp)[idx] = bf16_rne(v);
      }
    }
  }
}

// ---------------------------------------------------------------------------
__device__ __forceinline__ void cvt8(const float* in, unsigned short* out, long i) {
  f32x4 a = *(const f32x4*)(in + i * 8);
  f32x4 b = *(const f32x4*)(in + i * 8 + 4);
  u32x4 w;
  w[0] = pack2(a[0], a[1]); w[1] = pack2(a[2], a[3]);
  w[2] = pack2(b[0], b[1]); w[3] = pack2(b[2], b[3]);
  *(u32x4*)(out + i * 8) = w;
}

// mega_cvt3: weights (2048 blocks), query (4096), key (4096), bias (8),
// then OPTIONALLY value (4096 blocks) when launched with grid 14344.
__global__ __launch_bounds__(256) void mega_cvt3(
    const float* __restrict__ wq, const float* __restrict__ wk,
    const float* __restrict__ wv, const float* __restrict__ wo,
    const float* __restrict__ query, const float* __restrict__ key_,
    const float* __restrict__ value,
    const float* __restrict__ bq, const float* __restrict__ bk,
    unsigned short* __restrict__ Wb, unsigned short* __restrict__ qf,
    unsigned short* __restrict__ kf, unsigned short* __restrict__ vf,
    float* __restrict__ bqk)
{
  const int b = blockIdx.x;
  if (b < 2048) {
    const long i = (long)(b & 511) * 256 + threadIdx.x;
    if (b < 512)        cvt8(wq, Wb,            i);
    else if (b < 1024)  cvt8(wk, Wb + 1048576,  i);
    else if (b < 1536)  cvt8(wv, Wb + 2097152,  i);
    else                cvt8(wo, Wb + 3145728,  i);
  } else if (b < 6144) {
    cvt8(query, qf, (long)(b - 2048) * 256 + threadIdx.x);
  } else if (b < 10240) {
    cvt8(key_,  kf, (long)(b - 6144) * 256 + threadIdx.x);
  } else if (b < 10248) {
    const int t = (b - 10240) * 256 + threadIdx.x;
    if (t < 1024) bqk[t] = bq[t];
    else          bqk[t] = bk[t - 1024];
  } else {
    cvt8(value, vf, (long)(b - 10248) * 256 + threadIdx.x);
  }
}

__global__ __launch_bounds__(256) void cvt_f32_bf16(
    const float* __restrict__ in, unsigned short* __restrict__ out, int n8)
{
  const int i = blockIdx.x * 256 + threadIdx.x;
  if (i >= n8) return;
  cvt8(in, out, i);
}

// ---------------------------------------------------------------------------
__global__ __launch_bounds__(256) void softmax_inplace(unsigned short* __restrict__ P) {
  const long row = blockIdx.x;
  unsigned short* pr = P + row * 2048;
  const int tid = threadIdx.x;

  u32x4 raw = *(const u32x4*)&pr[tid * 8];
  float s[8];
  #pragma unroll
  for (int i = 0; i < 4; ++i) {
    unsigned int u = raw[i];
    s[2 * i]     = __builtin_bit_cast(float, u << 16);
    s[2 * i + 1] = __builtin_bit_cast(float, u & 0xFFFF0000u);
  }
  float m = s[0];
  #pragma unroll
  for (int i = 1; i < 8; ++i) m = fmaxf(m, s[i]);
  #pragma unroll
  for (int off = 32; off >= 1; off >>= 1) m = fmaxf(m, __shfl_xor(m, off));

  __shared__ float redm[4], reds[4];
  const int wid = tid >> 6, lane = tid & 63;
  if (lane == 0) redm[wid] = m;
  __syncthreads();
  m = fmaxf(fmaxf(redm[0], redm[1]), fmaxf(redm[2], redm[3]));

  float e[8], sum = 0.f;
  #pragma unroll
  for (int i = 0; i < 8; ++i) { e[i] = __expf(s[i] - m); sum += e[i]; }
  #pragma unroll
  for (int off = 32; off >= 1; off >>= 1) sum += __shfl_xor(sum, off);
  if (lane == 0) reds[wid] = sum;
  __syncthreads();
  sum = reds[0] + reds[1] + reds[2] + reds[3];
  const float inv = 1.0f / sum;

  u32x4 outw;
  #pragma unroll
  for (int i = 0; i < 4; ++i) outw[i] = pack2(e[2 * i] * inv, e[2 * i + 1] * inv);
  *(u32x4*)&pr[tid * 8] = outw;
}

// ---------------------------------------------------------------------------
extern "C" void kernel_launch(void* const* d_in, const int* in_sizes, int n_in,
                              void* d_out, int out_size, void* d_ws, size_t ws_size,
                              hipStream_t stream) {
  const float* query = (const float*)d_in[0];
  const float* key_  = (const float*)d_in[1];
  const float* value = (const float*)d_in[2];
  const float* Wq    = (const float*)d_in[3];
  const float* bq    = (const float*)d_in[4];
  const float* Wk    = (const float*)d_in[5];
  const float* bk    = (const float*)d_in[6];
  const float* Wv    = (const float*)d_in[7];
  const float* bv    = (const float*)d_in[8];
  const float* Wo    = (const float*)d_in[9];
  const float* bo    = (const float*)d_in[10];

  unsigned short* ws = (unsigned short*)d_ws;
  unsigned short* qf = ws;                        // [8192][1024] -> P lower
  unsigned short* kf = ws + 8388608;              // [8192][1024] -> P upper
  unsigned short* P  = ws;                        // [4][2048][2048]
  unsigned short* q  = ws + 16777216;             // [2][8.4M] q,k -> later o
  unsigned short* vT = ws + 33554432;             // [1024][8192]
  unsigned short* Wb = ws + 41943040;             // 4 x [1024][1024] bf16
  float*          bqk= (float*)(ws + 46137344);   // [2][1024] fp32
  unsigned short* o  = q;                         // overlays dead q

  // value-buffer placement: parallel (fresh tail region, cvt merged into
  // mega_cvt3) when ws is big enough; else serial fallback (overlay qf,
  // cvt after qkproj) -- identical math either way.
  const bool par = ws_size >= (size_t)(46141440 + 8388608) * 2;
  unsigned short* vf = par ? (ws + 46141440) : ws;

  const dim3 blk(256), blk8(512);

  // 0: all prologue conversions + bias copy in ONE dispatch
  mega_cvt3<<<dim3(par ? 14344 : 10248), blk, 0, stream>>>(
      Wq, Wk, Wv, Wo, query, key_, value, bq, bk, Wb, qf, kf, vf, bqk);

  // 1: [q;k] projections, z=2. M=8192, N=1024, K=1024. 256 blocks.
  gemm256<0><<<dim3(4, 32, 2), blk8, 0, stream>>>(qf, Wb, q,
      1024, 1024, 1024, 1024, 8388608L, 1048576L, 8388608L, 1024L, 1.0f, bqk, 1);

  // 2: fallback only -- convert value into region freed by qf
  if (!par)
    cvt_f32_bf16<<<dim3(4096), blk, 0, stream>>>(value, vf, 1048576);

  // 3: vT = Wv @ vf^T + bv. M=1024, N=8192, K=1024, bias per-row. 256 blocks.
  gemm8<0><<<dim3(64, 4, 1), blk8, 0, stream>>>(Wb + 2097152, vf, vT,
      1024, 1024, 1024, 8192, 0L, 0L, 0L, 0L, 1.0f, bv, 2);

  // 4: P = q @ k^T / 32, z=4. M=N=2048, K=1024. 256 blocks.
  gemm256<0><<<dim3(8, 8, 4), blk8, 0, stream>>>(q, q + 8388608, P,
      1024, 1024, 1024, 2048, 2097152L, 2097152L, 4194304L, 0L, 0.03125f, nullptr, 0);

  // 5: softmax rows in place (8192 rows x 2048)
  softmax_inplace<<<dim3(8192), blk, 0, stream>>>(P);

  // 6: o = P @ vT^T, z=4. M=2048, N=1024, K=2048. 256 blocks.
  gemm8<0><<<dim3(8, 8, 4), blk8, 0, stream>>>(P, vT, o,
      2048, 2048, 8192, 1024, 4194304L, 2048L, 2097152L, 0L, 1.0f, nullptr, 0);

  // 7: out = o @ Wo^T + bo (fp32 out). M=8192, N=1024, K=1024. 256 blocks.
  gemm8<1><<<dim3(8, 32, 1), blk8, 0, stream>>>(o, Wb + 3145728, d_out,
      1024, 1024, 1024, 1024, 0L, 0L, 0L, 0L, 1.0f, bo, 1);
}

// Round 14
// 226.001 us; speedup vs baseline: 1.0456x; 1.0339x over previous
//
#include <hip/hip_runtime.h>
#include <stdint.h>

// ---------------------------------------------------------------------------
// Single-head attention, B=4, S=2048, D=1024, fp32 in/out. bf16 MFMA pipeline.
//
//  0. mega_cvt3: fp32->bf16 Wq,Wk,Wv,Wo,query,key(,value if ws allows) + bias
//  1. [q;k] = [qf;kf] @ [Wq;Wk]^T + b    (z=2 batched)      [gemm256]
//  2. (fallback only) cvt value -> vf
//  3. vT = Wv @ vf^T + bv                 [1024,8192]        [gemm8]
//  4. P  = q @ k^T / 32 (z=4)             [4,2048,2048]      [gemm256]
//  5. softmax rows of P in place
//  6. o  = P @ vT^T (z=4)                                    [gemm8]
//  7. out= o @ Wo^T + bo -> d_out (fp32)                     [gemm8]
//
// R14: FREE-RUN K-loops (phase barriers removed). R7-R13 arithmetic showed
//   barrier-locked phases serialize the shared LDS pipe (8-wave read burst,
//   e.g. 12 reads/wave -> 1152cy) against the 621cy MFMA cluster: predicted
//   7800cy/tile == measured 7840. Fix: ONE barrier + one vmcnt per K-tile;
//   within the tile the compiler's fine-grained lgkmcnt (m97 asm evidence)
//   overlaps ds_reads and MFMAs -> per-tile ~ max(LDS 2816, MFMA 2483).
//   Safety: a wave at tile t's top barrier has consumed all t-1 reads
//   (lgkmcnt precedes each MFMA in program order), so staging the other
//   buffer after the barrier is race-free; top vmcnt waits loads issued a
//   full tile ago (free). MFMA order per-acc unchanged -> bit-identical.
// ---------------------------------------------------------------------------

typedef __bf16  bf16x8 __attribute__((ext_vector_type(8)));
typedef float   f32x4  __attribute__((ext_vector_type(4)));
typedef unsigned int u32x4 __attribute__((ext_vector_type(4)));

__device__ __forceinline__ unsigned short bf16_rne(float f) {
  unsigned int u = __builtin_bit_cast(unsigned int, f);
  u += 0x7FFFu + ((u >> 16) & 1u);
  return (unsigned short)(u >> 16);
}
__device__ __forceinline__ unsigned int pack2(float a, float b) {
  return (unsigned int)bf16_rne(a) | ((unsigned int)bf16_rne(b) << 16);
}
__device__ __forceinline__ void async16(const unsigned short* g, unsigned short* l) {
  __builtin_amdgcn_global_load_lds(
      (const __attribute__((address_space(1))) unsigned int*)g,
      (__attribute__((address_space(3))) unsigned int*)l,
      16, 0, 0);
}

#define FENCE() asm volatile("" ::: "memory")
#define BAR()   __builtin_amdgcn_s_barrier()

#define MFMA_ __builtin_amdgcn_mfma_f32_16x16x32_bf16

// T1: XCD-chunked bijective remap (m204), work linearized x-fastest.
#define T1_REMAP() \
  const int nx   = gridDim.x, ny = gridDim.y; \
  const int nwg  = nx * ny * gridDim.z; \
  const int orig = (blockIdx.z * ny + blockIdx.y) * nx + blockIdx.x; \
  const int xcd  = orig & 7, loc = orig >> 3; \
  const int qq   = nwg >> 3, rr = nwg & 7; \
  const int w    = (xcd < rr ? xcd * (qq + 1) : rr * (qq + 1) + (xcd - rr) * qq) + loc; \
  const int bxi  = w % nx; \
  const int byi  = (w / nx) % ny; \
  const int bzi  = w / (nx * ny);

// ---------------------------------------------------------------------------
// gemm256: C[z][m][n] = scale * sum_k A[z][m][k]*B[z][n][k] (+bias)
// M % 256 == 0, N % 256 == 0, K % 64 == 0, K >= 128.
// ---------------------------------------------------------------------------
template<int OUT_F32>
__global__ __launch_bounds__(512) void gemm256(
    const unsigned short* __restrict__ A, const unsigned short* __restrict__ B,
    void* __restrict__ Cp,
    int K, int lda, int ldb, int ldc,
    long sAz, long sBz, long sCz, long sBiasZ,
    float scale, const float* __restrict__ bias, int bias_mode)
{
  __shared__ unsigned short lds[2 * 32768];   // dbuf: A 16384 + B 16384 ushorts

  T1_REMAP();

  const int tid  = threadIdx.x;
  const int lane = tid & 63;
  const int wid  = tid >> 6;                  // 0..7
  const int bm   = byi * 256;
  const int bn   = bxi * 256;
  const long z   = bzi;

  const unsigned short* Az = A + z * sAz;
  const unsigned short* Bz = B + z * sBz;

  const int wm  = wid >> 2;                   // 0..1  (128 rows)
  const int wn  = wid & 3;                    // 0..3  (64 cols)
  const int al  = lane & 15;
  const int ah  = lane >> 4;
  const int al7 = lane & 7;

  const int swz = ((lane & 7) ^ ((lane >> 3) & 7)) << 3;
  const unsigned short* Apt = Az + (long)(bm + wid * 32 + (lane >> 3)) * lda + swz;
  const unsigned short* Bpt = Bz + (long)(bn + wid * 32 + (lane >> 3)) * ldb + swz;
  const long a8 = (long)lda * 8, b8 = (long)ldb * 8;

#define SALL(kt, stg) { \
    const unsigned short* pa_ = Apt + ((long)(kt) << 6); \
    const unsigned short* pb_ = Bpt + ((long)(kt) << 6); \
    async16(pa_,          (stg) + wid * 2048);        \
    async16(pa_ + a8,     (stg) + wid * 2048 + 512);  \
    async16(pa_ + 2 * a8, (stg) + wid * 2048 + 1024); \
    async16(pa_ + 3 * a8, (stg) + wid * 2048 + 1536); \
    async16(pb_,          (stg) + 16384 + wid * 2048);        \
    async16(pb_ + b8,     (stg) + 16384 + wid * 2048 + 512);  \
    async16(pb_ + 2 * b8, (stg) + 16384 + wid * 2048 + 1024); \
    async16(pb_ + 3 * b8, (stg) + 16384 + wid * 2048 + 1536); }

  // swizzled fragment reads: physical 16B unit = logical(kk*4+ah) ^ (row&7)
#define LDA2(v0, v1, mm) { const int r_ = (wm * 128 + (mm) * 16 + al) * 64; \
    v0 = *(const bf16x8*)&as[r_ + ((ah ^ al7) << 3)]; \
    v1 = *(const bf16x8*)&as[r_ + (((4 | ah) ^ al7) << 3)]; }
#define LDB2(v0, v1, nn) { const int r_ = (wn * 64 + (nn) * 16 + al) * 64; \
    v0 = *(const bf16x8*)&bs[r_ + ((ah ^ al7) << 3)]; \
    v1 = *(const bf16x8*)&bs[r_ + (((4 | ah) ^ al7) << 3)]; }
#define MM2(mi, ni, av0, av1, bv0, bv1) { \
    acc[mi][ni] = MFMA_(av0, bv0, acc[mi][ni], 0, 0, 0); \
    acc[mi][ni] = MFMA_(av1, bv1, acc[mi][ni], 0, 0, 0); }

  f32x4 acc[8][4] = {};
  const int nkt = K >> 6;

  // prologue: tile 0 into dbuf 0 (8 loads/wave in flight)
  SALL(0, lds);

  int cur = 0;
  for (int t = 0; t < nkt; ++t) {
    // tile t's loads were issued a full K-tile ago -> this drain is ~free.
    asm volatile("s_waitcnt vmcnt(0)" ::: "memory");
    BAR(); FENCE();

    const unsigned short* as  = lds + cur * 32768;
    const unsigned short* bs  = as + 16384;
    unsigned short*       stg = lds + (cur ^ 1) * 32768;

    // stage next tile first (earliest issue -> max latency hiding)
    if (t + 1 < nkt) SALL(t + 1, stg);

    bf16x8 a0k0, a0k1, a1k0, a1k1, a2k0, a2k1, a3k0, a3k1;
    bf16x8 b0k0, b0k1, b1k0, b1k1, b2k0, b2k1, b3k0, b3k1;

    // group 1: A m0-3 + B all; MFMAs m0-3 x n0-3 (compiler overlaps via
    // fine-grained lgkmcnt -- no barriers inside the tile)
    LDA2(a0k0, a0k1, 0); LDA2(a1k0, a1k1, 1); LDA2(a2k0, a2k1, 2); LDA2(a3k0, a3k1, 3);
    LDB2(b0k0, b0k1, 0); LDB2(b1k0, b1k1, 1); LDB2(b2k0, b2k1, 2); LDB2(b3k0, b3k1, 3);
    MM2(0,0, a0k0,a0k1, b0k0,b0k1); MM2(1,0, a1k0,a1k1, b0k0,b0k1);
    MM2(2,0, a2k0,a2k1, b0k0,b0k1); MM2(3,0, a3k0,a3k1, b0k0,b0k1);
    MM2(0,1, a0k0,a0k1, b1k0,b1k1); MM2(1,1, a1k0,a1k1, b1k0,b1k1);
    MM2(2,1, a2k0,a2k1, b1k0,b1k1); MM2(3,1, a3k0,a3k1, b1k0,b1k1);
    MM2(0,2, a0k0,a0k1, b2k0,b2k1); MM2(1,2, a1k0,a1k1, b2k0,b2k1);
    MM2(2,2, a2k0,a2k1, b2k0,b2k1); MM2(3,2, a3k0,a3k1, b2k0,b2k1);
    MM2(0,3, a0k0,a0k1, b3k0,b3k1); MM2(1,3, a1k0,a1k1, b3k0,b3k1);
    MM2(2,3, a2k0,a2k1, b3k0,b3k1); MM2(3,3, a3k0,a3k1, b3k0,b3k1);

    // group 2: A m4-7 (recycle a-frag registers); MFMAs m4-7 x n0-3
    LDA2(a0k0, a0k1, 4); LDA2(a1k0, a1k1, 5); LDA2(a2k0, a2k1, 6); LDA2(a3k0, a3k1, 7);
    MM2(4,0, a0k0,a0k1, b0k0,b0k1); MM2(5,0, a1k0,a1k1, b0k0,b0k1);
    MM2(6,0, a2k0,a2k1, b0k0,b0k1); MM2(7,0, a3k0,a3k1, b0k0,b0k1);
    MM2(4,1, a0k0,a0k1, b1k0,b1k1); MM2(5,1, a1k0,a1k1, b1k0,b1k1);
    MM2(6,1, a2k0,a2k1, b1k0,b1k1); MM2(7,1, a3k0,a3k1, b1k0,b1k1);
    MM2(4,2, a0k0,a0k1, b2k0,b2k1); MM2(5,2, a1k0,a1k1, b2k0,b2k1);
    MM2(6,2, a2k0,a2k1, b2k0,b2k1); MM2(7,2, a3k0,a3k1, b2k0,b2k1);
    MM2(4,3, a0k0,a0k1, b3k0,b3k1); MM2(5,3, a1k0,a1k1, b3k0,b3k1);
    MM2(6,3, a2k0,a2k1, b3k0,b3k1); MM2(7,3, a3k0,a3k1, b3k0,b3k1);

    cur ^= 1;
  }

  // Epilogue. C/D layout: col = lane&15, row = (lane>>4)*4 + j
  #pragma unroll
  for (int m = 0; m < 8; ++m) {
    #pragma unroll
    for (int n = 0; n < 4; ++n) {
      #pragma unroll
      for (int j = 0; j < 4; ++j) {
        const int grow = bm + wm * 128 + m * 16 + ah * 4 + j;
        const int gcol = bn + wn * 64 + n * 16 + al;
        float v = acc[m][n][j] * scale;
        if (bias_mode == 1)      v += bias[z * sBiasZ + gcol];
        else if (bias_mode == 2) v += bias[z * sBiasZ + grow];
        const long idx = z * sCz + (long)grow * ldc + gcol;
        if (OUT_F32) ((float*)Cp)[idx] = v;
        else         ((unsigned short*)Cp)[idx] = bf16_rne(v);
      }
    }
  }
}

// ---------------------------------------------------------------------------
// gemm8: free-run version. M % 256 == 0, N % 128 == 0, K % 64 == 0, K >= 192.
// ---------------------------------------------------------------------------
template<int OUT_F32>
__global__ __launch_bounds__(512) void gemm8(
    const unsigned short* __restrict__ A, const unsigned short* __restrict__ B,
    void* __restrict__ Cp,
    int K, int lda, int ldb, int ldc,
    long sAz, long sBz, long sCz, long sBiasZ,
    float scale, const float* __restrict__ bias, int bias_mode)
{
  __shared__ unsigned short lds[3 * 24576];   // 3-ring: A 16384 + B 8192 each

  T1_REMAP();

  const int tid  = threadIdx.x;
  const int lane = tid & 63;
  const int wid  = tid >> 6;                  // 0..7
  const int bm   = byi * 256;
  const int bn   = bxi * 128;
  const long z   = bzi;

  const unsigned short* Az = A + z * sAz;
  const unsigned short* Bz = B + z * sBz;

  const int wr  = (wid >> 1) * 64;
  const int wc  = (wid & 1)  * 64;
  const int al  = lane & 15;
  const int ah  = lane >> 4;
  const int al7 = lane & 7;

  const int swz = ((lane & 7) ^ ((lane >> 3) & 7)) << 3;
  const unsigned short* Apt = Az + (long)(bm + wid * 32 + (lane >> 3)) * lda + swz;
  const unsigned short* Bpt = Bz + (long)(bn + wid * 16 + (lane >> 3)) * ldb + swz;
  const long a8 = (long)lda * 8, b8 = (long)ldb * 8;

  f32x4 acc[4][4] = {};
  const int nkt = K >> 6;

#define STAGE_AB(kt, stg) { \
    const unsigned short* a_ = Apt + ((long)(kt) << 6); \
    const unsigned short* b_ = Bpt + ((long)(kt) << 6); \
    async16(a_,          (stg) + wid * 2048);        \
    async16(a_ + a8,     (stg) + wid * 2048 + 512);  \
    async16(a_ + 2 * a8, (stg) + wid * 2048 + 1024); \
    async16(a_ + 3 * a8, (stg) + wid * 2048 + 1536); \
    async16(b_,          (stg) + 16384 + wid * 1024); \
    async16(b_ + b8,     (stg) + 16384 + wid * 1024 + 512); }

#define LDA_(m) { const int r_ = (wr + (m) * 16 + al) * 64; \
    af##m##0 = *(const bf16x8*)&as[r_ + ((ah ^ al7) << 3)]; \
    af##m##1 = *(const bf16x8*)&as[r_ + (((4 | ah) ^ al7) << 3)]; }
#define LDB_(n) { const int r_ = (wc + (n) * 16 + al) * 64; \
    bf##n##0 = *(const bf16x8*)&bs[r_ + ((ah ^ al7) << 3)]; \
    bf##n##1 = *(const bf16x8*)&bs[r_ + (((4 | ah) ^ al7) << 3)]; }
#define MM(m, n) { \
    acc[m][n] = MFMA_(af##m##0, bf##n##0, acc[m][n], 0, 0, 0); \
    acc[m][n] = MFMA_(af##m##1, bf##n##1, acc[m][n], 0, 0, 0); }

  STAGE_AB(0, lds);
  STAGE_AB(1, lds + 24576);

  int cur = 0;
  for (int t = 0; t < nkt; ++t) {
    const int stb  = (cur >= 1) ? cur - 1 : cur + 2;   // (t+2)%3

    // tile t resident: allow only tile t+1's 6 loads outstanding.
    if (t + 1 < nkt) asm volatile("s_waitcnt vmcnt(6)" ::: "memory");
    else             asm volatile("s_waitcnt vmcnt(0)" ::: "memory");
    BAR(); FENCE();

    const unsigned short* as  = lds + cur * 24576;
    const unsigned short* bs  = as + 16384;
    unsigned short*       stg = lds + stb * 24576;

    if (t + 2 < nkt) STAGE_AB(t + 2, stg);

    bf16x8 af00, af01, af10, af11, af20, af21, af30, af31;
    bf16x8 bf00, bf01, bf10, bf11, bf20, bf21, bf30, bf31;

    LDA_(0); LDA_(1); LDA_(2); LDA_(3);
    LDB_(0); LDB_(1); LDB_(2); LDB_(3);
    MM(0,0); MM(1,0); MM(2,0); MM(3,0);
    MM(0,1); MM(1,1); MM(2,1); MM(3,1);
    MM(0,2); MM(1,2); MM(2,2); MM(3,2);
    MM(0,3); MM(1,3); MM(2,3); MM(3,3);

    cur = (cur == 2) ? 0 : cur + 1;
  }

  #pragma unroll
  for (int m = 0; m < 4; ++m) {
    #pragma unroll
    for (int n = 0; n < 4; ++n) {
      #pragma unroll
      for (int j = 0; j < 4; ++j) {
        const int grow = bm + wr + m * 16 + ah * 4 + j;
        const int gcol = bn + wc + n * 16 + al;
        float v = acc[m][n][j] * scale;
        if (bias_mode == 1)      v += bias[z * sBiasZ + gcol];
        else if (bias_mode == 2) v += bias[z * sBiasZ + grow];
        const long idx = z * sCz + (long)grow * ldc + gcol;
        if (OUT_F32) ((float*)Cp)[idx] = v;
        else         ((unsigned short*)Cp)[idx] = bf16_rne(v);
      }
    }
  }
}

// ---------------------------------------------------------------------------
__device__ __forceinline__ void cvt8(const float* in, unsigned short* out, long i) {
  f32x4 a = *(const f32x4*)(in + i * 8);
  f32x4 b = *(const f32x4*)(in + i * 8 + 4);
  u32x4 w;
  w[0] = pack2(a[0], a[1]); w[1] = pack2(a[2], a[3]);
  w[2] = pack2(b[0], b[1]); w[3] = pack2(b[2], b[3]);
  *(u32x4*)(out + i * 8) = w;
}

// mega_cvt3: weights (2048 blocks), query (4096), key (4096), bias (8),
// then OPTIONALLY value (4096 blocks) when launched with grid 14344.
__global__ __launch_bounds__(256) void mega_cvt3(
    const float* __restrict__ wq, const float* __restrict__ wk,
    const float* __restrict__ wv, const float* __restrict__ wo,
    const float* __restrict__ query, const float* __restrict__ key_,
    const float* __restrict__ value,
    const float* __restrict__ bq, const float* __restrict__ bk,
    unsigned short* __restrict__ Wb, unsigned short* __restrict__ qf,
    unsigned short* __restrict__ kf, unsigned short* __restrict__ vf,
    float* __restrict__ bqk)
{
  const int b = blockIdx.x;
  if (b < 2048) {
    const long i = (long)(b & 511) * 256 + threadIdx.x;
    if (b < 512)        cvt8(wq, Wb,            i);
    else if (b < 1024)  cvt8(wk, Wb + 1048576,  i);
    else if (b < 1536)  cvt8(wv, Wb + 2097152,  i);
    else                cvt8(wo, Wb + 3145728,  i);
  } else if (b < 6144) {
    cvt8(query, qf, (long)(b - 2048) * 256 + threadIdx.x);
  } else if (b < 10240) {
    cvt8(key_,  kf, (long)(b - 6144) * 256 + threadIdx.x);
  } else if (b < 10248) {
    const int t = (b - 10240) * 256 + threadIdx.x;
    if (t < 1024) bqk[t] = bq[t];
    else          bqk[t] = bk[t - 1024];
  } else {
    cvt8(value, vf, (long)(b - 10248) * 256 + threadIdx.x);
  }
}

__global__ __launch_bounds__(256) void cvt_f32_bf16(
    const float* __restrict__ in, unsigned short* __restrict__ out, int n8)
{
  const int i = blockIdx.x * 256 + threadIdx.x;
  if (i >= n8) return;
  cvt8(in, out, i);
}

// ---------------------------------------------------------------------------
__global__ __launch_bounds__(256) void softmax_inplace(unsigned short* __restrict__ P) {
  const long row = blockIdx.x;
  unsigned short* pr = P + row * 2048;
  const int tid = threadIdx.x;

  u32x4 raw = *(const u32x4*)&pr[tid * 8];
  float s[8];
  #pragma unroll
  for (int i = 0; i < 4; ++i) {
    unsigned int u = raw[i];
    s[2 * i]     = __builtin_bit_cast(float, u << 16);
    s[2 * i + 1] = __builtin_bit_cast(float, u & 0xFFFF0000u);
  }
  float m = s[0];
  #pragma unroll
  for (int i = 1; i < 8; ++i) m = fmaxf(m, s[i]);
  #pragma unroll
  for (int off = 32; off >= 1; off >>= 1) m = fmaxf(m, __shfl_xor(m, off));

  __shared__ float redm[4], reds[4];
  const int wid = tid >> 6, lane = tid & 63;
  if (lane == 0) redm[wid] = m;
  __syncthreads();
  m = fmaxf(fmaxf(redm[0], redm[1]), fmaxf(redm[2], redm[3]));

  float e[8], sum = 0.f;
  #pragma unroll
  for (int i = 0; i < 8; ++i) { e[i] = __expf(s[i] - m); sum += e[i]; }
  #pragma unroll
  for (int off = 32; off >= 1; off >>= 1) sum += __shfl_xor(sum, off);
  if (lane == 0) reds[wid] = sum;
  __syncthreads();
  sum = reds[0] + reds[1] + reds[2] + reds[3];
  const float inv = 1.0f / sum;

  u32x4 outw;
  #pragma unroll
  for (int i = 0; i < 4; ++i) outw[i] = pack2(e[2 * i] * inv, e[2 * i + 1] * inv);
  *(u32x4*)&pr[tid * 8] = outw;
}

// ---------------------------------------------------------------------------
extern "C" void kernel_launch(void* const* d_in, const int* in_sizes, int n_in,
                              void* d_out, int out_size, void* d_ws, size_t ws_size,
                              hipStream_t stream) {
  const float* query = (const float*)d_in[0];
  const float* key_  = (const float*)d_in[1];
  const float* value = (const float*)d_in[2];
  const float* Wq    = (const float*)d_in[3];
  const float* bq    = (const float*)d_in[4];
  const float* Wk    = (const float*)d_in[5];
  const float* bk    = (const float*)d_in[6];
  const float* Wv    = (const float*)d_in[7];
  const float* bv    = (const float*)d_in[8];
  const float* Wo    = (const float*)d_in[9];
  const float* bo    = (const float*)d_in[10];

  unsigned short* ws = (unsigned short*)d_ws;
  unsigned short* qf = ws;                        // [8192][1024] -> P lower
  unsigned short* kf = ws + 8388608;              // [8192][1024] -> P upper
  unsigned short* P  = ws;                        // [4][2048][2048]
  unsigned short* q  = ws + 16777216;             // [2][8.4M] q,k -> later o
  unsigned short* vT = ws + 33554432;             // [1024][8192]
  unsigned short* Wb = ws + 41943040;             // 4 x [1024][1024] bf16
  float*          bqk= (float*)(ws + 46137344);   // [2][1024] fp32
  unsigned short* o  = q;                         // overlays dead q

  const bool par = ws_size >= (size_t)(46141440 + 8388608) * 2;
  unsigned short* vf = par ? (ws + 46141440) : ws;

  const dim3 blk(256), blk8(512);

  // 0: all prologue conversions + bias copy in ONE dispatch
  mega_cvt3<<<dim3(par ? 14344 : 10248), blk, 0, stream>>>(
      Wq, Wk, Wv, Wo, query, key_, value, bq, bk, Wb, qf, kf, vf, bqk);

  // 1: [q;k] projections, z=2. M=8192, N=1024, K=1024. 256 blocks.
  gemm256<0><<<dim3(4, 32, 2), blk8, 0, stream>>>(qf, Wb, q,
      1024, 1024, 1024, 1024, 8388608L, 1048576L, 8388608L, 1024L, 1.0f, bqk, 1);

  // 2: fallback only -- convert value into region freed by qf
  if (!par)
    cvt_f32_bf16<<<dim3(4096), blk, 0, stream>>>(value, vf, 1048576);

  // 3: vT = Wv @ vf^T + bv. M=1024, N=8192, K=1024, bias per-row. 256 blocks.
  gemm8<0><<<dim3(64, 4, 1), blk8, 0, stream>>>(Wb + 2097152, vf, vT,
      1024, 1024, 1024, 8192, 0L, 0L, 0L, 0L, 1.0f, bv, 2);

  // 4: P = q @ k^T / 32, z=4. M=N=2048, K=1024. 256 blocks.
  gemm256<0><<<dim3(8, 8, 4), blk8, 0, stream>>>(q, q + 8388608, P,
      1024, 1024, 1024, 2048, 2097152L, 2097152L, 4194304L, 0L, 0.03125f, nullptr, 0);

  // 5: softmax rows in place (8192 rows x 2048)
  softmax_inplace<<<dim3(8192), blk, 0, stream>>>(P);

  // 6: o = P @ vT^T, z=4. M=2048, N=1024, K=2048. 256 blocks.
  gemm8<0><<<dim3(8, 8, 4), blk8, 0, stream>>>(P, vT, o,
      2048, 2048, 8192, 1024, 4194304L, 2048L, 2097152L, 0L, 1.0f, nullptr, 0);

  // 7: out = o @ Wo^T + bo (fp32 out). M=8192, N=1024, K=1024. 256 blocks.
  gemm8<1><<<dim3(8, 32, 1), blk8, 0, stream>>>(o, Wb + 3145728, d_out,
      1024, 1024, 1024, 1024, 0L, 0L, 0L, 0L, 1.0f, bo, 1);
}

// Round 15
// 223.424 us; speedup vs baseline: 1.0576x; 1.0115x over previous
//
#include <hip/hip_runtime.h>
#include <stdint.h>

// ---------------------------------------------------------------------------
// Single-head attention, B=4, S=2048, D=1024, fp32 in/out. bf16 MFMA pipeline.
//
//  0. mega_cvt3: fp32->bf16 Wq,Wk,Wv,Wo,query,key(,value if ws allows) + bias
//  1. [q;k] = [qf;kf] @ [Wq;Wk]^T + b    (z=2 batched)      [gemm256]
//  2. (fallback only) cvt value -> vf
//  3. vT = Wv @ vf^T + bv                 [1024,8192]        [gemm8]
//  4. P  = q @ k^T / 32 (z=4)             [4,2048,2048]      [gemm256]
//  5. softmax rows of P in place
//  6. o  = P @ vT^T (z=4)                                    [gemm8]
//  7. out= o @ Wo^T + bo -> d_out (fp32)                     [gemm8]
//
// R15: READS-FIRST bodies. Hypothesis from R5-R14 invariance (~8000cy/tile
//   across 10 schedules): the compiler cannot disambiguate LDS between
//   global_load_lds DMA writes and ds_reads, so any body that issues the
//   STAGE before the reads gets a compiler-inserted s_waitcnt vmcnt(0)
//   before the first ds_read -- waiting on the JUST-issued loads every
//   tile. Fix: {drain; BAR; ALL ds_reads; stage(t+1); MFMAs} -- no DMA
//   outstanding when reads issue; DMA hides under the MFMA block + next
//   tile. MFMA order per-accumulator unchanged -> bit-identical numerics.
// ---------------------------------------------------------------------------

typedef __bf16  bf16x8 __attribute__((ext_vector_type(8)));
typedef float   f32x4  __attribute__((ext_vector_type(4)));
typedef unsigned int u32x4 __attribute__((ext_vector_type(4)));

__device__ __forceinline__ unsigned short bf16_rne(float f) {
  unsigned int u = __builtin_bit_cast(unsigned int, f);
  u += 0x7FFFu + ((u >> 16) & 1u);
  return (unsigned short)(u >> 16);
}
__device__ __forceinline__ unsigned int pack2(float a, float b) {
  return (unsigned int)bf16_rne(a) | ((unsigned int)bf16_rne(b) << 16);
}
__device__ __forceinline__ void async16(const unsigned short* g, unsigned short* l) {
  __builtin_amdgcn_global_load_lds(
      (const __attribute__((address_space(1))) unsigned int*)g,
      (__attribute__((address_space(3))) unsigned int*)l,
      16, 0, 0);
}

#define FENCE() asm volatile("" ::: "memory")
#define BAR()   __builtin_amdgcn_s_barrier()

#define MFMA_ __builtin_amdgcn_mfma_f32_16x16x32_bf16

// T1: XCD-chunked bijective remap (m204), work linearized x-fastest.
#define T1_REMAP() \
  const int nx   = gridDim.x, ny = gridDim.y; \
  const int nwg  = nx * ny * gridDim.z; \
  const int orig = (blockIdx.z * ny + blockIdx.y) * nx + blockIdx.x; \
  const int xcd  = orig & 7, loc = orig >> 3; \
  const int qq   = nwg >> 3, rr = nwg & 7; \
  const int w    = (xcd < rr ? xcd * (qq + 1) : rr * (qq + 1) + (xcd - rr) * qq) + loc; \
  const int bxi  = w % nx; \
  const int byi  = (w / nx) % ny; \
  const int bzi  = w / (nx * ny);

// ---------------------------------------------------------------------------
// gemm256: C[z][m][n] = scale * sum_k A[z][m][k]*B[z][n][k] (+bias)
// M % 256 == 0, N % 256 == 0, K % 64 == 0, K >= 128.
// ---------------------------------------------------------------------------
template<int OUT_F32>
__global__ __launch_bounds__(512) void gemm256(
    const unsigned short* __restrict__ A, const unsigned short* __restrict__ B,
    void* __restrict__ Cp,
    int K, int lda, int ldb, int ldc,
    long sAz, long sBz, long sCz, long sBiasZ,
    float scale, const float* __restrict__ bias, int bias_mode)
{
  __shared__ unsigned short lds[2 * 32768];   // dbuf: A 16384 + B 16384 ushorts

  T1_REMAP();

  const int tid  = threadIdx.x;
  const int lane = tid & 63;
  const int wid  = tid >> 6;                  // 0..7
  const int bm   = byi * 256;
  const int bn   = bxi * 256;
  const long z   = bzi;

  const unsigned short* Az = A + z * sAz;
  const unsigned short* Bz = B + z * sBz;

  const int wm  = wid >> 2;                   // 0..1  (128 rows)
  const int wn  = wid & 3;                    // 0..3  (64 cols)
  const int al  = lane & 15;
  const int ah  = lane >> 4;
  const int al7 = lane & 7;

  const int swz = ((lane & 7) ^ ((lane >> 3) & 7)) << 3;
  const unsigned short* Apt = Az + (long)(bm + wid * 32 + (lane >> 3)) * lda + swz;
  const unsigned short* Bpt = Bz + (long)(bn + wid * 32 + (lane >> 3)) * ldb + swz;
  const long a8 = (long)lda * 8, b8 = (long)ldb * 8;

#define SALL(kt, stg) { \
    const unsigned short* pa_ = Apt + ((long)(kt) << 6); \
    const unsigned short* pb_ = Bpt + ((long)(kt) << 6); \
    async16(pa_,          (stg) + wid * 2048);        \
    async16(pa_ + a8,     (stg) + wid * 2048 + 512);  \
    async16(pa_ + 2 * a8, (stg) + wid * 2048 + 1024); \
    async16(pa_ + 3 * a8, (stg) + wid * 2048 + 1536); \
    async16(pb_,          (stg) + 16384 + wid * 2048);        \
    async16(pb_ + b8,     (stg) + 16384 + wid * 2048 + 512);  \
    async16(pb_ + 2 * b8, (stg) + 16384 + wid * 2048 + 1024); \
    async16(pb_ + 3 * b8, (stg) + 16384 + wid * 2048 + 1536); }

  // swizzled fragment reads: physical 16B unit = logical(kk*4+ah) ^ (row&7)
#define LDA2(v0, v1, mm) { const int r_ = (wm * 128 + (mm) * 16 + al) * 64; \
    v0 = *(const bf16x8*)&as[r_ + ((ah ^ al7) << 3)]; \
    v1 = *(const bf16x8*)&as[r_ + (((4 | ah) ^ al7) << 3)]; }
#define LDB2(v0, v1, nn) { const int r_ = (wn * 64 + (nn) * 16 + al) * 64; \
    v0 = *(const bf16x8*)&bs[r_ + ((ah ^ al7) << 3)]; \
    v1 = *(const bf16x8*)&bs[r_ + (((4 | ah) ^ al7) << 3)]; }
#define MM2(mi, ni, av0, av1, bv0, bv1) { \
    acc[mi][ni] = MFMA_(av0, bv0, acc[mi][ni], 0, 0, 0); \
    acc[mi][ni] = MFMA_(av1, bv1, acc[mi][ni], 0, 0, 0); }

  f32x4 acc[8][4] = {};
  const int nkt = K >> 6;

  // prologue: tile 0 into dbuf 0 (8 loads/wave in flight)
  SALL(0, lds);

  int cur = 0;
  for (int t = 0; t < nkt; ++t) {
    // drain tile t's loads (issued a full tile ago except t=0)
    asm volatile("s_waitcnt vmcnt(0)" ::: "memory");
    BAR(); FENCE();

    const unsigned short* as  = lds + cur * 32768;
    const unsigned short* bs  = as + 16384;
    unsigned short*       stg = lds + (cur ^ 1) * 32768;

    // ---- ALL ds_reads first (no DMA outstanding -> no compiler drain)
    bf16x8 a0k0, a0k1, a1k0, a1k1, a2k0, a2k1, a3k0, a3k1;
    bf16x8 a4k0, a4k1, a5k0, a5k1, a6k0, a6k1, a7k0, a7k1;
    bf16x8 b0k0, b0k1, b1k0, b1k1, b2k0, b2k1, b3k0, b3k1;
    LDA2(a0k0, a0k1, 0); LDA2(a1k0, a1k1, 1); LDA2(a2k0, a2k1, 2); LDA2(a3k0, a3k1, 3);
    LDA2(a4k0, a4k1, 4); LDA2(a5k0, a5k1, 5); LDA2(a6k0, a6k1, 6); LDA2(a7k0, a7k1, 7);
    LDB2(b0k0, b0k1, 0); LDB2(b1k0, b1k1, 1); LDB2(b2k0, b2k1, 2); LDB2(b3k0, b3k1, 3);

    // ---- stage next tile AFTER the reads (DMA hides under MFMAs)
    if (t + 1 < nkt) SALL(t + 1, stg);

    // ---- 64 MFMAs (register-only; compiler overlaps with read latency)
    MM2(0,0, a0k0,a0k1, b0k0,b0k1); MM2(1,0, a1k0,a1k1, b0k0,b0k1);
    MM2(2,0, a2k0,a2k1, b0k0,b0k1); MM2(3,0, a3k0,a3k1, b0k0,b0k1);
    MM2(4,0, a4k0,a4k1, b0k0,b0k1); MM2(5,0, a5k0,a5k1, b0k0,b0k1);
    MM2(6,0, a6k0,a6k1, b0k0,b0k1); MM2(7,0, a7k0,a7k1, b0k0,b0k1);
    MM2(0,1, a0k0,a0k1, b1k0,b1k1); MM2(1,1, a1k0,a1k1, b1k0,b1k1);
    MM2(2,1, a2k0,a2k1, b1k0,b1k1); MM2(3,1, a3k0,a3k1, b1k0,b1k1);
    MM2(4,1, a4k0,a4k1, b1k0,b1k1); MM2(5,1, a5k0,a5k1, b1k0,b1k1);
    MM2(6,1, a6k0,a6k1, b1k0,b1k1); MM2(7,1, a7k0,a7k1, b1k0,b1k1);
    MM2(0,2, a0k0,a0k1, b2k0,b2k1); MM2(1,2, a1k0,a1k1, b2k0,b2k1);
    MM2(2,2, a2k0,a2k1, b2k0,b2k1); MM2(3,2, a3k0,a3k1, b2k0,b2k1);
    MM2(4,2, a4k0,a4k1, b2k0,b2k1); MM2(5,2, a5k0,a5k1, b2k0,b2k1);
    MM2(6,2, a6k0,a6k1, b2k0,b2k1); MM2(7,2, a7k0,a7k1, b2k0,b2k1);
    MM2(0,3, a0k0,a0k1, b3k0,b3k1); MM2(1,3, a1k0,a1k1, b3k0,b3k1);
    MM2(2,3, a2k0,a2k1, b3k0,b3k1); MM2(3,3, a3k0,a3k1, b3k0,b3k1);
    MM2(4,3, a4k0,a4k1, b3k0,b3k1); MM2(5,3, a5k0,a5k1, b3k0,b3k1);
    MM2(6,3, a6k0,a6k1, b3k0,b3k1); MM2(7,3, a7k0,a7k1, b3k0,b3k1);

    cur ^= 1;
  }

  // Epilogue. C/D layout: col = lane&15, row = (lane>>4)*4 + j
  #pragma unroll
  for (int m = 0; m < 8; ++m) {
    #pragma unroll
    for (int n = 0; n < 4; ++n) {
      #pragma unroll
      for (int j = 0; j < 4; ++j) {
        const int grow = bm + wm * 128 + m * 16 + ah * 4 + j;
        const int gcol = bn + wn * 64 + n * 16 + al;
        float v = acc[m][n][j] * scale;
        if (bias_mode == 1)      v += bias[z * sBiasZ + gcol];
        else if (bias_mode == 2) v += bias[z * sBiasZ + grow];
        const long idx = z * sCz + (long)grow * ldc + gcol;
        if (OUT_F32) ((float*)Cp)[idx] = v;
        else         ((unsigned short*)Cp)[idx] = bf16_rne(v);
      }
    }
  }
}

// ---------------------------------------------------------------------------
// gemm8: reads-first version. M % 256 == 0, N % 128 == 0, K % 64 == 0, K>=192.
// ---------------------------------------------------------------------------
template<int OUT_F32>
__global__ __launch_bounds__(512) void gemm8(
    const unsigned short* __restrict__ A, const unsigned short* __restrict__ B,
    void* __restrict__ Cp,
    int K, int lda, int ldb, int ldc,
    long sAz, long sBz, long sCz, long sBiasZ,
    float scale, const float* __restrict__ bias, int bias_mode)
{
  __shared__ unsigned short lds[3 * 24576];   // 3-ring: A 16384 + B 8192 each

  T1_REMAP();

  const int tid  = threadIdx.x;
  const int lane = tid & 63;
  const int wid  = tid >> 6;                  // 0..7
  const int bm   = byi * 256;
  const int bn   = bxi * 128;
  const long z   = bzi;

  const unsigned short* Az = A + z * sAz;
  const unsigned short* Bz = B + z * sBz;

  const int wr  = (wid >> 1) * 64;
  const int wc  = (wid & 1)  * 64;
  const int al  = lane & 15;
  const int ah  = lane >> 4;
  const int al7 = lane & 7;

  const int swz = ((lane & 7) ^ ((lane >> 3) & 7)) << 3;
  const unsigned short* Apt = Az + (long)(bm + wid * 32 + (lane >> 3)) * lda + swz;
  const unsigned short* Bpt = Bz + (long)(bn + wid * 16 + (lane >> 3)) * ldb + swz;
  const long a8 = (long)lda * 8, b8 = (long)ldb * 8;

  f32x4 acc[4][4] = {};
  const int nkt = K >> 6;

#define STAGE_AB(kt, stg) { \
    const unsigned short* a_ = Apt + ((long)(kt) << 6); \
    const unsigned short* b_ = Bpt + ((long)(kt) << 6); \
    async16(a_,          (stg) + wid * 2048);        \
    async16(a_ + a8,     (stg) + wid * 2048 + 512);  \
    async16(a_ + 2 * a8, (stg) + wid * 2048 + 1024); \
    async16(a_ + 3 * a8, (stg) + wid * 2048 + 1536); \
    async16(b_,          (stg) + 16384 + wid * 1024); \
    async16(b_ + b8,     (stg) + 16384 + wid * 1024 + 512); }

#define LDA_(m) { const int r_ = (wr + (m) * 16 + al) * 64; \
    af##m##0 = *(const bf16x8*)&as[r_ + ((ah ^ al7) << 3)]; \
    af##m##1 = *(const bf16x8*)&as[r_ + (((4 | ah) ^ al7) << 3)]; }
#define LDB_(n) { const int r_ = (wc + (n) * 16 + al) * 64; \
    bf##n##0 = *(const bf16x8*)&bs[r_ + ((ah ^ al7) << 3)]; \
    bf##n##1 = *(const bf16x8*)&bs[r_ + (((4 | ah) ^ al7) << 3)]; }
#define MM(m, n) { \
    acc[m][n] = MFMA_(af##m##0, bf##n##0, acc[m][n], 0, 0, 0); \
    acc[m][n] = MFMA_(af##m##1, bf##n##1, acc[m][n], 0, 0, 0); }

  STAGE_AB(0, lds);
  STAGE_AB(1, lds + 24576);

  int cur = 0;
  for (int t = 0; t < nkt; ++t) {
    const int stb  = (cur >= 1) ? cur - 1 : cur + 2;   // (t+2)%3

    // tile t resident: allow only tile t+1's 6 loads outstanding.
    if (t + 1 < nkt) asm volatile("s_waitcnt vmcnt(6)" ::: "memory");
    else             asm volatile("s_waitcnt vmcnt(0)" ::: "memory");
    BAR(); FENCE();

    const unsigned short* as  = lds + cur * 24576;
    const unsigned short* bs  = as + 16384;
    unsigned short*       stg = lds + stb * 24576;

    // ---- all 16 ds_reads first
    bf16x8 af00, af01, af10, af11, af20, af21, af30, af31;
    bf16x8 bf00, bf01, bf10, bf11, bf20, bf21, bf30, bf31;
    LDA_(0); LDA_(1); LDA_(2); LDA_(3);
    LDB_(0); LDB_(1); LDB_(2); LDB_(3);

    // ---- stage tile t+2 AFTER the reads
    if (t + 2 < nkt) STAGE_AB(t + 2, stg);

    MM(0,0); MM(1,0); MM(2,0); MM(3,0);
    MM(0,1); MM(1,1); MM(2,1); MM(3,1);
    MM(0,2); MM(1,2); MM(2,2); MM(3,2);
    MM(0,3); MM(1,3); MM(2,3); MM(3,3);

    cur = (cur == 2) ? 0 : cur + 1;
  }

  #pragma unroll
  for (int m = 0; m < 4; ++m) {
    #pragma unroll
    for (int n = 0; n < 4; ++n) {
      #pragma unroll
      for (int j = 0; j < 4; ++j) {
        const int grow = bm + wr + m * 16 + ah * 4 + j;
        const int gcol = bn + wc + n * 16 + al;
        float v = acc[m][n][j] * scale;
        if (bias_mode == 1)      v += bias[z * sBiasZ + gcol];
        else if (bias_mode == 2) v += bias[z * sBiasZ + grow];
        const long idx = z * sCz + (long)grow * ldc + gcol;
        if (OUT_F32) ((float*)Cp)[idx] = v;
        else         ((unsigned short*)Cp)[idx] = bf16_rne(v);
      }
    }
  }
}

// ---------------------------------------------------------------------------
__device__ __forceinline__ void cvt8(const float* in, unsigned short* out, long i) {
  f32x4 a = *(const f32x4*)(in + i * 8);
  f32x4 b = *(const f32x4*)(in + i * 8 + 4);
  u32x4 w;
  w[0] = pack2(a[0], a[1]); w[1] = pack2(a[2], a[3]);
  w[2] = pack2(b[0], b[1]); w[3] = pack2(b[2], b[3]);
  *(u32x4*)(out + i * 8) = w;
}

// mega_cvt3: weights (2048 blocks), query (4096), key (4096), bias (8),
// then OPTIONALLY value (4096 blocks) when launched with grid 14344.
__global__ __launch_bounds__(256) void mega_cvt3(
    const float* __restrict__ wq, const float* __restrict__ wk,
    const float* __restrict__ wv, const float* __restrict__ wo,
    const float* __restrict__ query, const float* __restrict__ key_,
    const float* __restrict__ value,
    const float* __restrict__ bq, const float* __restrict__ bk,
    unsigned short* __restrict__ Wb, unsigned short* __restrict__ qf,
    unsigned short* __restrict__ kf, unsigned short* __restrict__ vf,
    float* __restrict__ bqk)
{
  const int b = blockIdx.x;
  if (b < 2048) {
    const long i = (long)(b & 511) * 256 + threadIdx.x;
    if (b < 512)        cvt8(wq, Wb,            i);
    else if (b < 1024)  cvt8(wk, Wb + 1048576,  i);
    else if (b < 1536)  cvt8(wv, Wb + 2097152,  i);
    else                cvt8(wo, Wb + 3145728,  i);
  } else if (b < 6144) {
    cvt8(query, qf, (long)(b - 2048) * 256 + threadIdx.x);
  } else if (b < 10240) {
    cvt8(key_,  kf, (long)(b - 6144) * 256 + threadIdx.x);
  } else if (b < 10248) {
    const int t = (b - 10240) * 256 + threadIdx.x;
    if (t < 1024) bqk[t] = bq[t];
    else          bqk[t] = bk[t - 1024];
  } else {
    cvt8(value, vf, (long)(b - 10248) * 256 + threadIdx.x);
  }
}

__global__ __launch_bounds__(256) void cvt_f32_bf16(
    const float* __restrict__ in, unsigned short* __restrict__ out, int n8)
{
  const int i = blockIdx.x * 256 + threadIdx.x;
  if (i >= n8) return;
  cvt8(in, out, i);
}

// ---------------------------------------------------------------------------
__global__ __launch_bounds__(256) void softmax_inplace(unsigned short* __restrict__ P) {
  const long row = blockIdx.x;
  unsigned short* pr = P + row * 2048;
  const int tid = threadIdx.x;

  u32x4 raw = *(const u32x4*)&pr[tid * 8];
  float s[8];
  #pragma unroll
  for (int i = 0; i < 4; ++i) {
    unsigned int u = raw[i];
    s[2 * i]     = __builtin_bit_cast(float, u << 16);
    s[2 * i + 1] = __builtin_bit_cast(float, u & 0xFFFF0000u);
  }
  float m = s[0];
  #pragma unroll
  for (int i = 1; i < 8; ++i) m = fmaxf(m, s[i]);
  #pragma unroll
  for (int off = 32; off >= 1; off >>= 1) m = fmaxf(m, __shfl_xor(m, off));

  __shared__ float redm[4], reds[4];
  const int wid = tid >> 6, lane = tid & 63;
  if (lane == 0) redm[wid] = m;
  __syncthreads();
  m = fmaxf(fmaxf(redm[0], redm[1]), fmaxf(redm[2], redm[3]));

  float e[8], sum = 0.f;
  #pragma unroll
  for (int i = 0; i < 8; ++i) { e[i] = __expf(s[i] - m); sum += e[i]; }
  #pragma unroll
  for (int off = 32; off >= 1; off >>= 1) sum += __shfl_xor(sum, off);
  if (lane == 0) reds[wid] = sum;
  __syncthreads();
  sum = reds[0] + reds[1] + reds[2] + reds[3];
  const float inv = 1.0f / sum;

  u32x4 outw;
  #pragma unroll
  for (int i = 0; i < 4; ++i) outw[i] = pack2(e[2 * i] * inv, e[2 * i + 1] * inv);
  *(u32x4*)&pr[tid * 8] = outw;
}

// ---------------------------------------------------------------------------
extern "C" void kernel_launch(void* const* d_in, const int* in_sizes, int n_in,
                              void* d_out, int out_size, void* d_ws, size_t ws_size,
                              hipStream_t stream) {
  const float* query = (const float*)d_in[0];
  const float* key_  = (const float*)d_in[1];
  const float* value = (const float*)d_in[2];
  const float* Wq    = (const float*)d_in[3];
  const float* bq    = (const float*)d_in[4];
  const float* Wk    = (const float*)d_in[5];
  const float* bk    = (const float*)d_in[6];
  const float* Wv    = (const float*)d_in[7];
  const float* bv    = (const float*)d_in[8];
  const float* Wo    = (const float*)d_in[9];
  const float* bo    = (const float*)d_in[10];

  unsigned short* ws = (unsigned short*)d_ws;
  unsigned short* qf = ws;                        // [8192][1024] -> P lower
  unsigned short* kf = ws + 8388608;              // [8192][1024] -> P upper
  unsigned short* P  = ws;                        // [4][2048][2048]
  unsigned short* q  = ws + 16777216;             // [2][8.4M] q,k -> later o
  unsigned short* vT = ws + 33554432;             // [1024][8192]
  unsigned short* Wb = ws + 41943040;             // 4 x [1024][1024] bf16
  float*          bqk= (float*)(ws + 46137344);   // [2][1024] fp32
  unsigned short* o  = q;                         // overlays dead q

  const bool par = ws_size >= (size_t)(46141440 + 8388608) * 2;
  unsigned short* vf = par ? (ws + 46141440) : ws;

  const dim3 blk(256), blk8(512);

  // 0: all prologue conversions + bias copy in ONE dispatch
  mega_cvt3<<<dim3(par ? 14344 : 10248), blk, 0, stream>>>(
      Wq, Wk, Wv, Wo, query, key_, value, bq, bk, Wb, qf, kf, vf, bqk);

  // 1: [q;k] projections, z=2. M=8192, N=1024, K=1024. 256 blocks.
  gemm256<0><<<dim3(4, 32, 2), blk8, 0, stream>>>(qf, Wb, q,
      1024, 1024, 1024, 1024, 8388608L, 1048576L, 8388608L, 1024L, 1.0f, bqk, 1);

  // 2: fallback only -- convert value into region freed by qf
  if (!par)
    cvt_f32_bf16<<<dim3(4096), blk, 0, stream>>>(value, vf, 1048576);

  // 3: vT = Wv @ vf^T + bv. M=1024, N=8192, K=1024, bias per-row. 256 blocks.
  gemm8<0><<<dim3(64, 4, 1), blk8, 0, stream>>>(Wb + 2097152, vf, vT,
      1024, 1024, 1024, 8192, 0L, 0L, 0L, 0L, 1.0f, bv, 2);

  // 4: P = q @ k^T / 32, z=4. M=N=2048, K=1024. 256 blocks.
  gemm256<0><<<dim3(8, 8, 4), blk8, 0, stream>>>(q, q + 8388608, P,
      1024, 1024, 1024, 2048, 2097152L, 2097152L, 4194304L, 0L, 0.03125f, nullptr, 0);

  // 5: softmax rows in place (8192 rows x 2048)
  softmax_inplace<<<dim3(8192), blk, 0, stream>>>(P);

  // 6: o = P @ vT^T, z=4. M=2048, N=1024, K=2048. 256 blocks.
  gemm8<0><<<dim3(8, 8, 4), blk8, 0, stream>>>(P, vT, o,
      2048, 2048, 8192, 1024, 4194304L, 2048L, 2097152L, 0L, 1.0f, nullptr, 0);

  // 7: out = o @ Wo^T + bo (fp32 out). M=8192, N=1024, K=1024. 256 blocks.
  gemm8<1><<<dim3(8, 32, 1), blk8, 0, stream>>>(o, Wb + 3145728, d_out,
      1024, 1024, 1024, 1024, 0L, 0L, 0L, 0L, 1.0f, bo, 1);
}

// Round 16
// 200.901 us; speedup vs baseline: 1.1762x; 1.1121x over previous
//
#include <hip/hip_runtime.h>
#include <stdint.h>

// ---------------------------------------------------------------------------
// Single-head attention, B=4, S=2048, D=1024, fp32 in/out. bf16 MFMA pipeline.
//
//  0. mega_cvt3: fp32->bf16 Wq,Wk,Wv,Wo,query,key(,value if ws allows) + bias
//  1. dual: [q;k] projections (gemm256 body) || vT = Wv@vf^T (gemm8 body)
//     -- one 512-block dispatch; the two 256-block GEMMs are independent.
//     (fallback: serial qkproj -> cvt value -> vT)
//  2. P  = q @ k^T / 32 (z=4)             [4,2048,2048]      [gemm256]
//  3. softmax rows of P in place
//  4. o  = P @ vT^T (z=4)                                    [gemm8]
//  5. out= o @ Wo^T + bo -> d_out (fp32)                     [gemm8]
//
// Engines at documented plateau (R2-R15: eleven schedule variants, all
// 53-98us; ~643 TF == guide m233's 2-phase structural ceiling; m201
// derived-waits escape not reproducible, matching learn_hip m232).
// gemm256: BM=BN=256 BK=64 dbuf, reads-first free-run, T1 remap, swizzle.
// gemm8:   BM=256 BN=128 BK=64 3-ring, vmcnt(6), same techniques.
// ---------------------------------------------------------------------------

typedef __bf16  bf16x8 __attribute__((ext_vector_type(8)));
typedef float   f32x4  __attribute__((ext_vector_type(4)));
typedef unsigned int u32x4 __attribute__((ext_vector_type(4)));

__device__ __forceinline__ unsigned short bf16_rne(float f) {
  unsigned int u = __builtin_bit_cast(unsigned int, f);
  u += 0x7FFFu + ((u >> 16) & 1u);
  return (unsigned short)(u >> 16);
}
__device__ __forceinline__ unsigned int pack2(float a, float b) {
  return (unsigned int)bf16_rne(a) | ((unsigned int)bf16_rne(b) << 16);
}
__device__ __forceinline__ void async16(const unsigned short* g, unsigned short* l) {
  __builtin_amdgcn_global_load_lds(
      (const __attribute__((address_space(1))) unsigned int*)g,
      (__attribute__((address_space(3))) unsigned int*)l,
      16, 0, 0);
}

#define FENCE() asm volatile("" ::: "memory")
#define BAR()   __builtin_amdgcn_s_barrier()
#define MFMA_   __builtin_amdgcn_mfma_f32_16x16x32_bf16

// T1 bijective XCD remap from explicit (nx, ny, nwg, orig)
#define T1_ARGS() \
  const int xcd = orig & 7, loc = orig >> 3; \
  const int qq  = nwg >> 3, rr = nwg & 7; \
  const int w   = (xcd < rr ? xcd * (qq + 1) : rr * (qq + 1) + (xcd - rr) * qq) + loc; \
  const int bxi = w % nx; \
  const int byi = (w / nx) % ny; \
  const int bzi = w / (nx * ny);

// ---------------------------------------------------------------------------
// gemm256 body (R15 verbatim, LDS + grid coords parameterized)
// needs lds >= 2*32768 ushorts. M%256==0, N%256==0, K%64==0.
// ---------------------------------------------------------------------------
template<int OUT_F32>
__device__ __forceinline__ void gbody256(
    unsigned short* __restrict__ lds,
    const unsigned short* __restrict__ A, const unsigned short* __restrict__ B,
    void* __restrict__ Cp,
    int K, int lda, int ldb, int ldc,
    long sAz, long sBz, long sCz, long sBiasZ,
    float scale, const float* __restrict__ bias, int bias_mode,
    int nx, int ny, int nwg, int orig)
{
  T1_ARGS();

  const int tid  = threadIdx.x;
  const int lane = tid & 63;
  const int wid  = tid >> 6;                  // 0..7
  const int bm   = byi * 256;
  const int bn   = bxi * 256;
  const long z   = bzi;

  const unsigned short* Az = A + z * sAz;
  const unsigned short* Bz = B + z * sBz;

  const int wm  = wid >> 2;
  const int wn  = wid & 3;
  const int al  = lane & 15;
  const int ah  = lane >> 4;
  const int al7 = lane & 7;

  const int swz = ((lane & 7) ^ ((lane >> 3) & 7)) << 3;
  const unsigned short* Apt = Az + (long)(bm + wid * 32 + (lane >> 3)) * lda + swz;
  const unsigned short* Bpt = Bz + (long)(bn + wid * 32 + (lane >> 3)) * ldb + swz;
  const long a8 = (long)lda * 8, b8 = (long)ldb * 8;

#define SALL(kt, stg) { \
    const unsigned short* pa_ = Apt + ((long)(kt) << 6); \
    const unsigned short* pb_ = Bpt + ((long)(kt) << 6); \
    async16(pa_,          (stg) + wid * 2048);        \
    async16(pa_ + a8,     (stg) + wid * 2048 + 512);  \
    async16(pa_ + 2 * a8, (stg) + wid * 2048 + 1024); \
    async16(pa_ + 3 * a8, (stg) + wid * 2048 + 1536); \
    async16(pb_,          (stg) + 16384 + wid * 2048);        \
    async16(pb_ + b8,     (stg) + 16384 + wid * 2048 + 512);  \
    async16(pb_ + 2 * b8, (stg) + 16384 + wid * 2048 + 1024); \
    async16(pb_ + 3 * b8, (stg) + 16384 + wid * 2048 + 1536); }

#define LDA2(v0, v1, mm) { const int r_ = (wm * 128 + (mm) * 16 + al) * 64; \
    v0 = *(const bf16x8*)&as[r_ + ((ah ^ al7) << 3)]; \
    v1 = *(const bf16x8*)&as[r_ + (((4 | ah) ^ al7) << 3)]; }
#define LDB2(v0, v1, nn) { const int r_ = (wn * 64 + (nn) * 16 + al) * 64; \
    v0 = *(const bf16x8*)&bs[r_ + ((ah ^ al7) << 3)]; \
    v1 = *(const bf16x8*)&bs[r_ + (((4 | ah) ^ al7) << 3)]; }
#define MM2(mi, ni, av0, av1, bv0, bv1) { \
    acc[mi][ni] = MFMA_(av0, bv0, acc[mi][ni], 0, 0, 0); \
    acc[mi][ni] = MFMA_(av1, bv1, acc[mi][ni], 0, 0, 0); }

  f32x4 acc[8][4] = {};
  const int nkt = K >> 6;

  SALL(0, lds);

  int cur = 0;
  for (int t = 0; t < nkt; ++t) {
    asm volatile("s_waitcnt vmcnt(0)" ::: "memory");
    BAR(); FENCE();

    const unsigned short* as  = lds + cur * 32768;
    const unsigned short* bs  = as + 16384;
    unsigned short*       stg = lds + (cur ^ 1) * 32768;

    bf16x8 a0k0, a0k1, a1k0, a1k1, a2k0, a2k1, a3k0, a3k1;
    bf16x8 a4k0, a4k1, a5k0, a5k1, a6k0, a6k1, a7k0, a7k1;
    bf16x8 b0k0, b0k1, b1k0, b1k1, b2k0, b2k1, b3k0, b3k1;
    LDA2(a0k0, a0k1, 0); LDA2(a1k0, a1k1, 1); LDA2(a2k0, a2k1, 2); LDA2(a3k0, a3k1, 3);
    LDA2(a4k0, a4k1, 4); LDA2(a5k0, a5k1, 5); LDA2(a6k0, a6k1, 6); LDA2(a7k0, a7k1, 7);
    LDB2(b0k0, b0k1, 0); LDB2(b1k0, b1k1, 1); LDB2(b2k0, b2k1, 2); LDB2(b3k0, b3k1, 3);

    if (t + 1 < nkt) SALL(t + 1, stg);

    MM2(0,0, a0k0,a0k1, b0k0,b0k1); MM2(1,0, a1k0,a1k1, b0k0,b0k1);
    MM2(2,0, a2k0,a2k1, b0k0,b0k1); MM2(3,0, a3k0,a3k1, b0k0,b0k1);
    MM2(4,0, a4k0,a4k1, b0k0,b0k1); MM2(5,0, a5k0,a5k1, b0k0,b0k1);
    MM2(6,0, a6k0,a6k1, b0k0,b0k1); MM2(7,0, a7k0,a7k1, b0k0,b0k1);
    MM2(0,1, a0k0,a0k1, b1k0,b1k1); MM2(1,1, a1k0,a1k1, b1k0,b1k1);
    MM2(2,1, a2k0,a2k1, b1k0,b1k1); MM2(3,1, a3k0,a3k1, b1k0,b1k1);
    MM2(4,1, a4k0,a4k1, b1k0,b1k1); MM2(5,1, a5k0,a5k1, b1k0,b1k1);
    MM2(6,1, a6k0,a6k1, b1k0,b1k1); MM2(7,1, a7k0,a7k1, b1k0,b1k1);
    MM2(0,2, a0k0,a0k1, b2k0,b2k1); MM2(1,2, a1k0,a1k1, b2k0,b2k1);
    MM2(2,2, a2k0,a2k1, b2k0,b2k1); MM2(3,2, a3k0,a3k1, b2k0,b2k1);
    MM2(4,2, a4k0,a4k1, b2k0,b2k1); MM2(5,2, a5k0,a5k1, b2k0,b2k1);
    MM2(6,2, a6k0,a6k1, b2k0,b2k1); MM2(7,2, a7k0,a7k1, b2k0,b2k1);
    MM2(0,3, a0k0,a0k1, b3k0,b3k1); MM2(1,3, a1k0,a1k1, b3k0,b3k1);
    MM2(2,3, a2k0,a2k1, b3k0,b3k1); MM2(3,3, a3k0,a3k1, b3k0,b3k1);
    MM2(4,3, a4k0,a4k1, b3k0,b3k1); MM2(5,3, a5k0,a5k1, b3k0,b3k1);
    MM2(6,3, a6k0,a6k1, b3k0,b3k1); MM2(7,3, a7k0,a7k1, b3k0,b3k1);

    cur ^= 1;
  }

  #pragma unroll
  for (int m = 0; m < 8; ++m) {
    #pragma unroll
    for (int n = 0; n < 4; ++n) {
      #pragma unroll
      for (int j = 0; j < 4; ++j) {
        const int grow = bm + wm * 128 + m * 16 + ah * 4 + j;
        const int gcol = bn + wn * 64 + n * 16 + al;
        float v = acc[m][n][j] * scale;
        if (bias_mode == 1)      v += bias[z * sBiasZ + gcol];
        else if (bias_mode == 2) v += bias[z * sBiasZ + grow];
        const long idx = z * sCz + (long)grow * ldc + gcol;
        if (OUT_F32) ((float*)Cp)[idx] = v;
        else         ((unsigned short*)Cp)[idx] = bf16_rne(v);
      }
    }
  }
}

// ---------------------------------------------------------------------------
// gemm8 body (R15 verbatim, parameterized). lds >= 3*24576 ushorts.
// M%256==0, N%128==0, K%64==0, K>=192.
// ---------------------------------------------------------------------------
template<int OUT_F32>
__device__ __forceinline__ void gbody8(
    unsigned short* __restrict__ lds,
    const unsigned short* __restrict__ A, const unsigned short* __restrict__ B,
    void* __restrict__ Cp,
    int K, int lda, int ldb, int ldc,
    long sAz, long sBz, long sCz, long sBiasZ,
    float scale, const float* __restrict__ bias, int bias_mode,
    int nx, int ny, int nwg, int orig)
{
  T1_ARGS();

  const int tid  = threadIdx.x;
  const int lane = tid & 63;
  const int wid  = tid >> 6;                  // 0..7
  const int bm   = byi * 256;
  const int bn   = bxi * 128;
  const long z   = bzi;

  const unsigned short* Az = A + z * sAz;
  const unsigned short* Bz = B + z * sBz;

  const int wr  = (wid >> 1) * 64;
  const int wc  = (wid & 1)  * 64;
  const int al  = lane & 15;
  const int ah  = lane >> 4;
  const int al7 = lane & 7;

  const int swz = ((lane & 7) ^ ((lane >> 3) & 7)) << 3;
  const unsigned short* Apt = Az + (long)(bm + wid * 32 + (lane >> 3)) * lda + swz;
  const unsigned short* Bpt = Bz + (long)(bn + wid * 16 + (lane >> 3)) * ldb + swz;
  const long a8 = (long)lda * 8, b8 = (long)ldb * 8;

  f32x4 acc[4][4] = {};
  const int nkt = K >> 6;

#define STAGE_AB(kt, stg) { \
    const unsigned short* a_ = Apt + ((long)(kt) << 6); \
    const unsigned short* b_ = Bpt + ((long)(kt) << 6); \
    async16(a_,          (stg) + wid * 2048);        \
    async16(a_ + a8,     (stg) + wid * 2048 + 512);  \
    async16(a_ + 2 * a8, (stg) + wid * 2048 + 1024); \
    async16(a_ + 3 * a8, (stg) + wid * 2048 + 1536); \
    async16(b_,          (stg) + 16384 + wid * 1024); \
    async16(b_ + b8,     (stg) + 16384 + wid * 1024 + 512); }

#define LDA_(m) { const int r_ = (wr + (m) * 16 + al) * 64; \
    af##m##0 = *(const bf16x8*)&as[r_ + ((ah ^ al7) << 3)]; \
    af##m##1 = *(const bf16x8*)&as[r_ + (((4 | ah) ^ al7) << 3)]; }
#define LDB_(n) { const int r_ = (wc + (n) * 16 + al) * 64; \
    bf##n##0 = *(const bf16x8*)&bs[r_ + ((ah ^ al7) << 3)]; \
    bf##n##1 = *(const bf16x8*)&bs[r_ + (((4 | ah) ^ al7) << 3)]; }
#define MM(m, n) { \
    acc[m][n] = MFMA_(af##m##0, bf##n##0, acc[m][n], 0, 0, 0); \
    acc[m][n] = MFMA_(af##m##1, bf##n##1, acc[m][n], 0, 0, 0); }

  STAGE_AB(0, lds);
  STAGE_AB(1, lds + 24576);

  int cur = 0;
  for (int t = 0; t < nkt; ++t) {
    const int stb  = (cur >= 1) ? cur - 1 : cur + 2;   // (t+2)%3

    if (t + 1 < nkt) asm volatile("s_waitcnt vmcnt(6)" ::: "memory");
    else             asm volatile("s_waitcnt vmcnt(0)" ::: "memory");
    BAR(); FENCE();

    const unsigned short* as  = lds + cur * 24576;
    const unsigned short* bs  = as + 16384;
    unsigned short*       stg = lds + stb * 24576;

    bf16x8 af00, af01, af10, af11, af20, af21, af30, af31;
    bf16x8 bf00, bf01, bf10, bf11, bf20, bf21, bf30, bf31;
    LDA_(0); LDA_(1); LDA_(2); LDA_(3);
    LDB_(0); LDB_(1); LDB_(2); LDB_(3);

    if (t + 2 < nkt) STAGE_AB(t + 2, stg);

    MM(0,0); MM(1,0); MM(2,0); MM(3,0);
    MM(0,1); MM(1,1); MM(2,1); MM(3,1);
    MM(0,2); MM(1,2); MM(2,2); MM(3,2);
    MM(0,3); MM(1,3); MM(2,3); MM(3,3);

    cur = (cur == 2) ? 0 : cur + 1;
  }

  #pragma unroll
  for (int m = 0; m < 4; ++m) {
    #pragma unroll
    for (int n = 0; n < 4; ++n) {
      #pragma unroll
      for (int j = 0; j < 4; ++j) {
        const int grow = bm + wr + m * 16 + ah * 4 + j;
        const int gcol = bn + wc + n * 16 + al;
        float v = acc[m][n][j] * scale;
        if (bias_mode == 1)      v += bias[z * sBiasZ + gcol];
        else if (bias_mode == 2) v += bias[z * sBiasZ + grow];
        const long idx = z * sCz + (long)grow * ldc + gcol;
        if (OUT_F32) ((float*)Cp)[idx] = v;
        else         ((unsigned short*)Cp)[idx] = bf16_rne(v);
      }
    }
  }
}

// ---------------------------------------------------------------------------
// standalone wrappers
// ---------------------------------------------------------------------------
template<int OUT_F32>
__global__ __launch_bounds__(512) void gemm256(
    const unsigned short* __restrict__ A, const unsigned short* __restrict__ B,
    void* __restrict__ Cp, int K, int lda, int ldb, int ldc,
    long sAz, long sBz, long sCz, long sBiasZ,
    float scale, const float* __restrict__ bias, int bias_mode)
{
  __shared__ unsigned short lds[2 * 32768];
  const int nx = gridDim.x, ny = gridDim.y;
  const int nwg = nx * ny * gridDim.z;
  const int orig = ((int)blockIdx.z * ny + blockIdx.y) * nx + blockIdx.x;
  gbody256<OUT_F32>(lds, A, B, Cp, K, lda, ldb, ldc, sAz, sBz, sCz, sBiasZ,
                    scale, bias, bias_mode, nx, ny, nwg, orig);
}

template<int OUT_F32>
__global__ __launch_bounds__(512) void gemm8(
    const unsigned short* __restrict__ A, const unsigned short* __restrict__ B,
    void* __restrict__ Cp, int K, int lda, int ldb, int ldc,
    long sAz, long sBz, long sCz, long sBiasZ,
    float scale, const float* __restrict__ bias, int bias_mode)
{
  __shared__ unsigned short lds[3 * 24576];
  const int nx = gridDim.x, ny = gridDim.y;
  const int nwg = nx * ny * gridDim.z;
  const int orig = ((int)blockIdx.z * ny + blockIdx.y) * nx + blockIdx.x;
  gbody8<OUT_F32>(lds, A, B, Cp, K, lda, ldb, ldc, sAz, sBz, sCz, sBiasZ,
                  scale, bias, bias_mode, nx, ny, nwg, orig);
}

// dual: blocks [0,256) = qkproj (gemm256 body, z=2), [256,512) = vT (gemm8).
// 256 % 8 == 0, so orig&7 == hw_block&7 -> T1 XCD assumption holds per half.
__global__ __launch_bounds__(512) void dual_qk_vt(
    const unsigned short* __restrict__ qf, const unsigned short* __restrict__ Wb,
    unsigned short* __restrict__ q, const float* __restrict__ bqk,
    const unsigned short* __restrict__ Wv, const unsigned short* __restrict__ vf,
    unsigned short* __restrict__ vT, const float* __restrict__ bv)
{
  __shared__ unsigned short lds[3 * 24576];   // 144KB: covers both bodies
  const int bid = blockIdx.x;
  if (bid < 256) {
    // qkproj: M=8192, N=1024, K=1024, z=2; grid-equiv (4,32,2)
    gbody256<0>(lds, qf, Wb, q, 1024, 1024, 1024, 1024,
                8388608L, 1048576L, 8388608L, 1024L, 1.0f, bqk, 1,
                4, 32, 256, bid);
  } else {
    // vT = Wv @ vf^T + bv: M=1024, N=8192, K=1024; grid-equiv (64,4,1)
    gbody8<0>(lds, Wv, vf, vT, 1024, 1024, 1024, 8192,
              0L, 0L, 0L, 0L, 1.0f, bv, 2,
              64, 4, 256, bid - 256);
  }
}

// ---------------------------------------------------------------------------
__device__ __forceinline__ void cvt8(const float* in, unsigned short* out, long i) {
  f32x4 a = *(const f32x4*)(in + i * 8);
  f32x4 b = *(const f32x4*)(in + i * 8 + 4);
  u32x4 w;
  w[0] = pack2(a[0], a[1]); w[1] = pack2(a[2], a[3]);
  w[2] = pack2(b[0], b[1]); w[3] = pack2(b[2], b[3]);
  *(u32x4*)(out + i * 8) = w;
}

// mega_cvt3: weights (2048 blocks), query (4096), key (4096), bias (8),
// then OPTIONALLY value (4096 blocks) when launched with grid 14344.
__global__ __launch_bounds__(256) void mega_cvt3(
    const float* __restrict__ wq, const float* __restrict__ wk,
    const float* __restrict__ wv, const float* __restrict__ wo,
    const float* __restrict__ query, const float* __restrict__ key_,
    const float* __restrict__ value,
    const float* __restrict__ bq, const float* __restrict__ bk,
    unsigned short* __restrict__ Wb, unsigned short* __restrict__ qf,
    unsigned short* __restrict__ kf, unsigned short* __restrict__ vf,
    float* __restrict__ bqk)
{
  const int b = blockIdx.x;
  if (b < 2048) {
    const long i = (long)(b & 511) * 256 + threadIdx.x;
    if (b < 512)        cvt8(wq, Wb,            i);
    else if (b < 1024)  cvt8(wk, Wb + 1048576,  i);
    else if (b < 1536)  cvt8(wv, Wb + 2097152,  i);
    else                cvt8(wo, Wb + 3145728,  i);
  } else if (b < 6144) {
    cvt8(query, qf, (long)(b - 2048) * 256 + threadIdx.x);
  } else if (b < 10240) {
    cvt8(key_,  kf, (long)(b - 6144) * 256 + threadIdx.x);
  } else if (b < 10248) {
    const int t = (b - 10240) * 256 + threadIdx.x;
    if (t < 1024) bqk[t] = bq[t];
    else          bqk[t] = bk[t - 1024];
  } else {
    cvt8(value, vf, (long)(b - 10248) * 256 + threadIdx.x);
  }
}

__global__ __launch_bounds__(256) void cvt_f32_bf16(
    const float* __restrict__ in, unsigned short* __restrict__ out, int n8)
{
  const int i = blockIdx.x * 256 + threadIdx.x;
  if (i >= n8) return;
  cvt8(in, out, i);
}

// ---------------------------------------------------------------------------
__global__ __launch_bounds__(256) void softmax_inplace(unsigned short* __restrict__ P) {
  const long row = blockIdx.x;
  unsigned short* pr = P + row * 2048;
  const int tid = threadIdx.x;

  u32x4 raw = *(const u32x4*)&pr[tid * 8];
  float s[8];
  #pragma unroll
  for (int i = 0; i < 4; ++i) {
    unsigned int u = raw[i];
    s[2 * i]     = __builtin_bit_cast(float, u << 16);
    s[2 * i + 1] = __builtin_bit_cast(float, u & 0xFFFF0000u);
  }
  float m = s[0];
  #pragma unroll
  for (int i = 1; i < 8; ++i) m = fmaxf(m, s[i]);
  #pragma unroll
  for (int off = 32; off >= 1; off >>= 1) m = fmaxf(m, __shfl_xor(m, off));

  __shared__ float redm[4], reds[4];
  const int wid = tid >> 6, lane = tid & 63;
  if (lane == 0) redm[wid] = m;
  __syncthreads();
  m = fmaxf(fmaxf(redm[0], redm[1]), fmaxf(redm[2], redm[3]));

  float e[8], sum = 0.f;
  #pragma unroll
  for (int i = 0; i < 8; ++i) { e[i] = __expf(s[i] - m); sum += e[i]; }
  #pragma unroll
  for (int off = 32; off >= 1; off >>= 1) sum += __shfl_xor(sum, off);
  if (lane == 0) reds[wid] = sum;
  __syncthreads();
  sum = reds[0] + reds[1] + reds[2] + reds[3];
  const float inv = 1.0f / sum;

  u32x4 outw;
  #pragma unroll
  for (int i = 0; i < 4; ++i) outw[i] = pack2(e[2 * i] * inv, e[2 * i + 1] * inv);
  *(u32x4*)&pr[tid * 8] = outw;
}

// ---------------------------------------------------------------------------
extern "C" void kernel_launch(void* const* d_in, const int* in_sizes, int n_in,
                              void* d_out, int out_size, void* d_ws, size_t ws_size,
                              hipStream_t stream) {
  const float* query = (const float*)d_in[0];
  const float* key_  = (const float*)d_in[1];
  const float* value = (const float*)d_in[2];
  const float* Wq    = (const float*)d_in[3];
  const float* bq    = (const float*)d_in[4];
  const float* Wk    = (const float*)d_in[5];
  const float* bk    = (const float*)d_in[6];
  const float* Wv    = (const float*)d_in[7];
  const float* bv    = (const float*)d_in[8];
  const float* Wo    = (const float*)d_in[9];
  const float* bo    = (const float*)d_in[10];

  unsigned short* ws = (unsigned short*)d_ws;
  unsigned short* qf = ws;                        // [8192][1024] -> P lower
  unsigned short* kf = ws + 8388608;              // [8192][1024] -> P upper
  unsigned short* P  = ws;                        // [4][2048][2048]
  unsigned short* q  = ws + 16777216;             // [2][8.4M] q,k -> later o
  unsigned short* vT = ws + 33554432;             // [1024][8192]
  unsigned short* Wb = ws + 41943040;             // 4 x [1024][1024] bf16
  float*          bqk= (float*)(ws + 46137344);   // [2][1024] fp32
  unsigned short* o  = q;                         // overlays dead q

  const bool par = ws_size >= (size_t)(46141440 + 8388608) * 2;
  unsigned short* vf = par ? (ws + 46141440) : ws;

  const dim3 blk(256), blk8(512);

  // 0: all prologue conversions + bias copy in ONE dispatch
  mega_cvt3<<<dim3(par ? 14344 : 10248), blk, 0, stream>>>(
      Wq, Wk, Wv, Wo, query, key_, value, bq, bk, Wb, qf, kf, vf, bqk);

  if (par) {
    // 1: qkproj || vT in one 512-block dispatch (independent GEMMs)
    dual_qk_vt<<<dim3(512), blk8, 0, stream>>>(qf, Wb, q, bqk,
                                               Wb + 2097152, vf, vT, bv);
  } else {
    // fallback: serial (vf overlays qf -> must follow qkproj)
    gemm256<0><<<dim3(4, 32, 2), blk8, 0, stream>>>(qf, Wb, q,
        1024, 1024, 1024, 1024, 8388608L, 1048576L, 8388608L, 1024L, 1.0f, bqk, 1);
    cvt_f32_bf16<<<dim3(4096), blk, 0, stream>>>(value, vf, 1048576);
    gemm8<0><<<dim3(64, 4, 1), blk8, 0, stream>>>(Wb + 2097152, vf, vT,
        1024, 1024, 1024, 8192, 0L, 0L, 0L, 0L, 1.0f, bv, 2);
  }

  // 2: P = q @ k^T / 32, z=4. M=N=2048, K=1024. 256 blocks.
  gemm256<0><<<dim3(8, 8, 4), blk8, 0, stream>>>(q, q + 8388608, P,
      1024, 1024, 1024, 2048, 2097152L, 2097152L, 4194304L, 0L, 0.03125f, nullptr, 0);

  // 3: softmax rows in place (8192 rows x 2048)
  softmax_inplace<<<dim3(8192), blk, 0, stream>>>(P);

  // 4: o = P @ vT^T, z=4. M=2048, N=1024, K=2048. 256 blocks.
  gemm8<0><<<dim3(8, 8, 4), blk8, 0, stream>>>(P, vT, o,
      2048, 2048, 8192, 1024, 4194304L, 2048L, 2097152L, 0L, 1.0f, nullptr, 0);

  // 5: out = o @ Wo^T + bo (fp32 out). M=8192, N=1024, K=1024. 256 blocks.
  gemm8<1><<<dim3(8, 32, 1), blk8, 0, stream>>>(o, Wb + 3145728, d_out,
      1024, 1024, 1024, 1024, 0L, 0L, 0L, 0L, 1.0f, bo, 1);
}

// Round 17
// 190.373 us; speedup vs baseline: 1.2413x; 1.0553x over previous
//
#include <hip/hip_runtime.h>
#include <stdint.h>

// ---------------------------------------------------------------------------
// Single-head attention, B=4, S=2048, D=1024, fp32 in/out. bf16 MFMA pipeline.
//
// R17 restructure (associativity): out = P (V Wo^T) + bo, with
//   W2T = Wo @ v^T  (shape-identical to the old vT kernel), so:
//  0. mega_cvt3: fp32->bf16 Wq,Wk,Wv,Wo,query,key,value + bias copy
//  1. dual1: [q;k] projections (gemm256, z=2) || v = vf@Wv^T+bv (gemm8)
//  2. dual2: P = q@k^T/32 (gemm256, z=4)     || W2T = Wo@v^T (gemm8)
//  3. softmax rows of P in place
//  4. out = P @ W2T^T + bo -> d_out (fp32)   (gemm8, K=2048, z=4)
// Same total FLOPs; removes one full GEMM stage from the critical path by
// pairing independent GEMMs (dual mechanism: R16 measured 905 vs 643 TF).
// Fallback (small ws): R16 exact serial path (vT + PV + outproj).
//
// Engines at documented plateau (R2-R15: eleven schedule variants, 53-98us;
// ~643 TF == guide m233's 2-phase structural ceiling).
// ---------------------------------------------------------------------------

typedef __bf16  bf16x8 __attribute__((ext_vector_type(8)));
typedef float   f32x4  __attribute__((ext_vector_type(4)));
typedef unsigned int u32x4 __attribute__((ext_vector_type(4)));

__device__ __forceinline__ unsigned short bf16_rne(float f) {
  unsigned int u = __builtin_bit_cast(unsigned int, f);
  u += 0x7FFFu + ((u >> 16) & 1u);
  return (unsigned short)(u >> 16);
}
__device__ __forceinline__ unsigned int pack2(float a, float b) {
  return (unsigned int)bf16_rne(a) | ((unsigned int)bf16_rne(b) << 16);
}
__device__ __forceinline__ void async16(const unsigned short* g, unsigned short* l) {
  __builtin_amdgcn_global_load_lds(
      (const __attribute__((address_space(1))) unsigned int*)g,
      (__attribute__((address_space(3))) unsigned int*)l,
      16, 0, 0);
}

#define FENCE() asm volatile("" ::: "memory")
#define BAR()   __builtin_amdgcn_s_barrier()
#define MFMA_   __builtin_amdgcn_mfma_f32_16x16x32_bf16

// T1 bijective XCD remap from explicit (nx, ny, nwg, orig)
#define T1_ARGS() \
  const int xcd = orig & 7, loc = orig >> 3; \
  const int qq  = nwg >> 3, rr = nwg & 7; \
  const int w   = (xcd < rr ? xcd * (qq + 1) : rr * (qq + 1) + (xcd - rr) * qq) + loc; \
  const int bxi = w % nx; \
  const int byi = (w / nx) % ny; \
  const int bzi = w / (nx * ny);

// ---------------------------------------------------------------------------
// gemm256 body. lds >= 2*32768 ushorts. M%256==0, N%256==0, K%64==0.
// ---------------------------------------------------------------------------
template<int OUT_F32>
__device__ __forceinline__ void gbody256(
    unsigned short* __restrict__ lds,
    const unsigned short* __restrict__ A, const unsigned short* __restrict__ B,
    void* __restrict__ Cp,
    int K, int lda, int ldb, int ldc,
    long sAz, long sBz, long sCz, long sBiasZ,
    float scale, const float* __restrict__ bias, int bias_mode,
    int nx, int ny, int nwg, int orig)
{
  T1_ARGS();

  const int tid  = threadIdx.x;
  const int lane = tid & 63;
  const int wid  = tid >> 6;                  // 0..7
  const int bm   = byi * 256;
  const int bn   = bxi * 256;
  const long z   = bzi;

  const unsigned short* Az = A + z * sAz;
  const unsigned short* Bz = B + z * sBz;

  const int wm  = wid >> 2;
  const int wn  = wid & 3;
  const int al  = lane & 15;
  const int ah  = lane >> 4;
  const int al7 = lane & 7;

  const int swz = ((lane & 7) ^ ((lane >> 3) & 7)) << 3;
  const unsigned short* Apt = Az + (long)(bm + wid * 32 + (lane >> 3)) * lda + swz;
  const unsigned short* Bpt = Bz + (long)(bn + wid * 32 + (lane >> 3)) * ldb + swz;
  const long a8 = (long)lda * 8, b8 = (long)ldb * 8;

#define SALL(kt, stg) { \
    const unsigned short* pa_ = Apt + ((long)(kt) << 6); \
    const unsigned short* pb_ = Bpt + ((long)(kt) << 6); \
    async16(pa_,          (stg) + wid * 2048);        \
    async16(pa_ + a8,     (stg) + wid * 2048 + 512);  \
    async16(pa_ + 2 * a8, (stg) + wid * 2048 + 1024); \
    async16(pa_ + 3 * a8, (stg) + wid * 2048 + 1536); \
    async16(pb_,          (stg) + 16384 + wid * 2048);        \
    async16(pb_ + b8,     (stg) + 16384 + wid * 2048 + 512);  \
    async16(pb_ + 2 * b8, (stg) + 16384 + wid * 2048 + 1024); \
    async16(pb_ + 3 * b8, (stg) + 16384 + wid * 2048 + 1536); }

#define LDA2(v0, v1, mm) { const int r_ = (wm * 128 + (mm) * 16 + al) * 64; \
    v0 = *(const bf16x8*)&as[r_ + ((ah ^ al7) << 3)]; \
    v1 = *(const bf16x8*)&as[r_ + (((4 | ah) ^ al7) << 3)]; }
#define LDB2(v0, v1, nn) { const int r_ = (wn * 64 + (nn) * 16 + al) * 64; \
    v0 = *(const bf16x8*)&bs[r_ + ((ah ^ al7) << 3)]; \
    v1 = *(const bf16x8*)&bs[r_ + (((4 | ah) ^ al7) << 3)]; }
#define MM2(mi, ni, av0, av1, bv0, bv1) { \
    acc[mi][ni] = MFMA_(av0, bv0, acc[mi][ni], 0, 0, 0); \
    acc[mi][ni] = MFMA_(av1, bv1, acc[mi][ni], 0, 0, 0); }

  f32x4 acc[8][4] = {};
  const int nkt = K >> 6;

  SALL(0, lds);

  int cur = 0;
  for (int t = 0; t < nkt; ++t) {
    asm volatile("s_waitcnt vmcnt(0)" ::: "memory");
    BAR(); FENCE();

    const unsigned short* as  = lds + cur * 32768;
    const unsigned short* bs  = as + 16384;
    unsigned short*       stg = lds + (cur ^ 1) * 32768;

    bf16x8 a0k0, a0k1, a1k0, a1k1, a2k0, a2k1, a3k0, a3k1;
    bf16x8 a4k0, a4k1, a5k0, a5k1, a6k0, a6k1, a7k0, a7k1;
    bf16x8 b0k0, b0k1, b1k0, b1k1, b2k0, b2k1, b3k0, b3k1;
    LDA2(a0k0, a0k1, 0); LDA2(a1k0, a1k1, 1); LDA2(a2k0, a2k1, 2); LDA2(a3k0, a3k1, 3);
    LDA2(a4k0, a4k1, 4); LDA2(a5k0, a5k1, 5); LDA2(a6k0, a6k1, 6); LDA2(a7k0, a7k1, 7);
    LDB2(b0k0, b0k1, 0); LDB2(b1k0, b1k1, 1); LDB2(b2k0, b2k1, 2); LDB2(b3k0, b3k1, 3);

    if (t + 1 < nkt) SALL(t + 1, stg);

    MM2(0,0, a0k0,a0k1, b0k0,b0k1); MM2(1,0, a1k0,a1k1, b0k0,b0k1);
    MM2(2,0, a2k0,a2k1, b0k0,b0k1); MM2(3,0, a3k0,a3k1, b0k0,b0k1);
    MM2(4,0, a4k0,a4k1, b0k0,b0k1); MM2(5,0, a5k0,a5k1, b0k0,b0k1);
    MM2(6,0, a6k0,a6k1, b0k0,b0k1); MM2(7,0, a7k0,a7k1, b0k0,b0k1);
    MM2(0,1, a0k0,a0k1, b1k0,b1k1); MM2(1,1, a1k0,a1k1, b1k0,b1k1);
    MM2(2,1, a2k0,a2k1, b1k0,b1k1); MM2(3,1, a3k0,a3k1, b1k0,b1k1);
    MM2(4,1, a4k0,a4k1, b1k0,b1k1); MM2(5,1, a5k0,a5k1, b1k0,b1k1);
    MM2(6,1, a6k0,a6k1, b1k0,b1k1); MM2(7,1, a7k0,a7k1, b1k0,b1k1);
    MM2(0,2, a0k0,a0k1, b2k0,b2k1); MM2(1,2, a1k0,a1k1, b2k0,b2k1);
    MM2(2,2, a2k0,a2k1, b2k0,b2k1); MM2(3,2, a3k0,a3k1, b2k0,b2k1);
    MM2(4,2, a4k0,a4k1, b2k0,b2k1); MM2(5,2, a5k0,a5k1, b2k0,b2k1);
    MM2(6,2, a6k0,a6k1, b2k0,b2k1); MM2(7,2, a7k0,a7k1, b2k0,b2k1);
    MM2(0,3, a0k0,a0k1, b3k0,b3k1); MM2(1,3, a1k0,a1k1, b3k0,b3k1);
    MM2(2,3, a2k0,a2k1, b3k0,b3k1); MM2(3,3, a3k0,a3k1, b3k0,b3k1);
    MM2(4,3, a4k0,a4k1, b3k0,b3k1); MM2(5,3, a5k0,a5k1, b3k0,b3k1);
    MM2(6,3, a6k0,a6k1, b3k0,b3k1); MM2(7,3, a7k0,a7k1, b3k0,b3k1);

    cur ^= 1;
  }

  #pragma unroll
  for (int m = 0; m < 8; ++m) {
    #pragma unroll
    for (int n = 0; n < 4; ++n) {
      #pragma unroll
      for (int j = 0; j < 4; ++j) {
        const int grow = bm + wm * 128 + m * 16 + ah * 4 + j;
        const int gcol = bn + wn * 64 + n * 16 + al;
        float v = acc[m][n][j] * scale;
        if (bias_mode == 1)      v += bias[z * sBiasZ + gcol];
        else if (bias_mode == 2) v += bias[z * sBiasZ + grow];
        const long idx = z * sCz + (long)grow * ldc + gcol;
        if (OUT_F32) ((float*)Cp)[idx] = v;
        else         ((unsigned short*)Cp)[idx] = bf16_rne(v);
      }
    }
  }
}

// ---------------------------------------------------------------------------
// gemm8 body. lds >= 3*24576 ushorts. M%256==0, N%128==0, K%64==0, K>=192.
// ---------------------------------------------------------------------------
template<int OUT_F32>
__device__ __forceinline__ void gbody8(
    unsigned short* __restrict__ lds,
    const unsigned short* __restrict__ A, const unsigned short* __restrict__ B,
    void* __restrict__ Cp,
    int K, int lda, int ldb, int ldc,
    long sAz, long sBz, long sCz, long sBiasZ,
    float scale, const float* __restrict__ bias, int bias_mode,
    int nx, int ny, int nwg, int orig)
{
  T1_ARGS();

  const int tid  = threadIdx.x;
  const int lane = tid & 63;
  const int wid  = tid >> 6;                  // 0..7
  const int bm   = byi * 256;
  const int bn   = bxi * 128;
  const long z   = bzi;

  const unsigned short* Az = A + z * sAz;
  const unsigned short* Bz = B + z * sBz;

  const int wr  = (wid >> 1) * 64;
  const int wc  = (wid & 1)  * 64;
  const int al  = lane & 15;
  const int ah  = lane >> 4;
  const int al7 = lane & 7;

  const int swz = ((lane & 7) ^ ((lane >> 3) & 7)) << 3;
  const unsigned short* Apt = Az + (long)(bm + wid * 32 + (lane >> 3)) * lda + swz;
  const unsigned short* Bpt = Bz + (long)(bn + wid * 16 + (lane >> 3)) * ldb + swz;
  const long a8 = (long)lda * 8, b8 = (long)ldb * 8;

  f32x4 acc[4][4] = {};
  const int nkt = K >> 6;

#define STAGE_AB(kt, stg) { \
    const unsigned short* a_ = Apt + ((long)(kt) << 6); \
    const unsigned short* b_ = Bpt + ((long)(kt) << 6); \
    async16(a_,          (stg) + wid * 2048);        \
    async16(a_ + a8,     (stg) + wid * 2048 + 512);  \
    async16(a_ + 2 * a8, (stg) + wid * 2048 + 1024); \
    async16(a_ + 3 * a8, (stg) + wid * 2048 + 1536); \
    async16(b_,          (stg) + 16384 + wid * 1024); \
    async16(b_ + b8,     (stg) + 16384 + wid * 1024 + 512); }

#define LDA_(m) { const int r_ = (wr + (m) * 16 + al) * 64; \
    af##m##0 = *(const bf16x8*)&as[r_ + ((ah ^ al7) << 3)]; \
    af##m##1 = *(const bf16x8*)&as[r_ + (((4 | ah) ^ al7) << 3)]; }
#define LDB_(n) { const int r_ = (wc + (n) * 16 + al) * 64; \
    bf##n##0 = *(const bf16x8*)&bs[r_ + ((ah ^ al7) << 3)]; \
    bf##n##1 = *(const bf16x8*)&bs[r_ + (((4 | ah) ^ al7) << 3)]; }
#define MM(m, n) { \
    acc[m][n] = MFMA_(af##m##0, bf##n##0, acc[m][n], 0, 0, 0); \
    acc[m][n] = MFMA_(af##m##1, bf##n##1, acc[m][n], 0, 0, 0); }

  STAGE_AB(0, lds);
  STAGE_AB(1, lds + 24576);

  int cur = 0;
  for (int t = 0; t < nkt; ++t) {
    const int stb  = (cur >= 1) ? cur - 1 : cur + 2;   // (t+2)%3

    if (t + 1 < nkt) asm volatile("s_waitcnt vmcnt(6)" ::: "memory");
    else             asm volatile("s_waitcnt vmcnt(0)" ::: "memory");
    BAR(); FENCE();

    const unsigned short* as  = lds + cur * 24576;
    const unsigned short* bs  = as + 16384;
    unsigned short*       stg = lds + stb * 24576;

    bf16x8 af00, af01, af10, af11, af20, af21, af30, af31;
    bf16x8 bf00, bf01, bf10, bf11, bf20, bf21, bf30, bf31;
    LDA_(0); LDA_(1); LDA_(2); LDA_(3);
    LDB_(0); LDB_(1); LDB_(2); LDB_(3);

    if (t + 2 < nkt) STAGE_AB(t + 2, stg);

    MM(0,0); MM(1,0); MM(2,0); MM(3,0);
    MM(0,1); MM(1,1); MM(2,1); MM(3,1);
    MM(0,2); MM(1,2); MM(2,2); MM(3,2);
    MM(0,3); MM(1,3); MM(2,3); MM(3,3);

    cur = (cur == 2) ? 0 : cur + 1;
  }

  #pragma unroll
  for (int m = 0; m < 4; ++m) {
    #pragma unroll
    for (int n = 0; n < 4; ++n) {
      #pragma unroll
      for (int j = 0; j < 4; ++j) {
        const int grow = bm + wr + m * 16 + ah * 4 + j;
        const int gcol = bn + wc + n * 16 + al;
        float v = acc[m][n][j] * scale;
        if (bias_mode == 1)      v += bias[z * sBiasZ + gcol];
        else if (bias_mode == 2) v += bias[z * sBiasZ + grow];
        const long idx = z * sCz + (long)grow * ldc + gcol;
        if (OUT_F32) ((float*)Cp)[idx] = v;
        else         ((unsigned short*)Cp)[idx] = bf16_rne(v);
      }
    }
  }
}

// ---------------------------------------------------------------------------
// standalone wrappers
// ---------------------------------------------------------------------------
template<int OUT_F32>
__global__ __launch_bounds__(512) void gemm256(
    const unsigned short* __restrict__ A, const unsigned short* __restrict__ B,
    void* __restrict__ Cp, int K, int lda, int ldb, int ldc,
    long sAz, long sBz, long sCz, long sBiasZ,
    float scale, const float* __restrict__ bias, int bias_mode)
{
  __shared__ unsigned short lds[2 * 32768];
  const int nx = gridDim.x, ny = gridDim.y;
  const int nwg = nx * ny * gridDim.z;
  const int orig = ((int)blockIdx.z * ny + blockIdx.y) * nx + blockIdx.x;
  gbody256<OUT_F32>(lds, A, B, Cp, K, lda, ldb, ldc, sAz, sBz, sCz, sBiasZ,
                    scale, bias, bias_mode, nx, ny, nwg, orig);
}

template<int OUT_F32>
__global__ __launch_bounds__(512) void gemm8(
    const unsigned short* __restrict__ A, const unsigned short* __restrict__ B,
    void* __restrict__ Cp, int K, int lda, int ldb, int ldc,
    long sAz, long sBz, long sCz, long sBiasZ,
    float scale, const float* __restrict__ bias, int bias_mode)
{
  __shared__ unsigned short lds[3 * 24576];
  const int nx = gridDim.x, ny = gridDim.y;
  const int nwg = nx * ny * gridDim.z;
  const int orig = ((int)blockIdx.z * ny + blockIdx.y) * nx + blockIdx.x;
  gbody8<OUT_F32>(lds, A, B, Cp, K, lda, ldb, ldc, sAz, sBz, sCz, sBiasZ,
                  scale, bias, bias_mode, nx, ny, nwg, orig);
}

// dual1: blocks [0,256) = qkproj (gemm256 body, z=2), [256,512) = vproj
// (gemm8 body: v = vf @ Wv^T + bv, [8192,1024]).
__global__ __launch_bounds__(512) void dual_qk_v(
    const unsigned short* __restrict__ qf, const unsigned short* __restrict__ Wb,
    unsigned short* __restrict__ q, const float* __restrict__ bqk,
    const unsigned short* __restrict__ vf, const unsigned short* __restrict__ Wv,
    unsigned short* __restrict__ v, const float* __restrict__ bv)
{
  __shared__ unsigned short lds[3 * 24576];   // 144KB: covers both bodies
  const int bid = blockIdx.x;
  if (bid < 256) {
    // qkproj: M=8192, N=1024, K=1024, z=2; grid-equiv (4,32,2)
    gbody256<0>(lds, qf, Wb, q, 1024, 1024, 1024, 1024,
                8388608L, 1048576L, 8388608L, 1024L, 1.0f, bqk, 1,
                4, 32, 256, bid);
  } else {
    // vproj: M=8192, N=1024, K=1024; grid-equiv (8,32,1)
    gbody8<0>(lds, vf, Wv, v, 1024, 1024, 1024, 1024,
              0L, 0L, 0L, 0L, 1.0f, bv, 1,
              8, 32, 256, bid - 256);
  }
}

// dual2: blocks [0,256) = scores (gemm256 body, z=4), [256,512) = W2T
// (gemm8 body: W2T = Wo @ v^T, [1024,8192]).
__global__ __launch_bounds__(512) void dual_sc_w2(
    const unsigned short* __restrict__ q, const unsigned short* __restrict__ k,
    unsigned short* __restrict__ P,
    const unsigned short* __restrict__ Wo, const unsigned short* __restrict__ v,
    unsigned short* __restrict__ W2T)
{
  __shared__ unsigned short lds[3 * 24576];
  const int bid = blockIdx.x;
  if (bid < 256) {
    // scores: M=N=2048, K=1024, z=4; grid-equiv (8,8,4)
    gbody256<0>(lds, q, k, P, 1024, 1024, 1024, 2048,
                2097152L, 2097152L, 4194304L, 0L, 0.03125f, nullptr, 0,
                8, 8, 256, bid);
  } else {
    // W2T = Wo @ v^T: M=1024, N=8192, K=1024; grid-equiv (64,4,1)
    gbody8<0>(lds, Wo, v, W2T, 1024, 1024, 1024, 8192,
              0L, 0L, 0L, 0L, 1.0f, nullptr, 0,
              64, 4, 256, bid - 256);
  }
}

// ---------------------------------------------------------------------------
__device__ __forceinline__ void cvt8(const float* in, unsigned short* out, long i) {
  f32x4 a = *(const f32x4*)(in + i * 8);
  f32x4 b = *(const f32x4*)(in + i * 8 + 4);
  u32x4 w;
  w[0] = pack2(a[0], a[1]); w[1] = pack2(a[2], a[3]);
  w[2] = pack2(b[0], b[1]); w[3] = pack2(b[2], b[3]);
  *(u32x4*)(out + i * 8) = w;
}

// mega_cvt3: weights (2048 blocks), query (4096), key (4096), bias (8),
// then OPTIONALLY value (4096 blocks) when launched with grid 14344.
__global__ __launch_bounds__(256) void mega_cvt3(
    const float* __restrict__ wq, const float* __restrict__ wk,
    const float* __restrict__ wv, const float* __restrict__ wo,
    const float* __restrict__ query, const float* __restrict__ key_,
    const float* __restrict__ value,
    const float* __restrict__ bq, const float* __restrict__ bk,
    unsigned short* __restrict__ Wb, unsigned short* __restrict__ qf,
    unsigned short* __restrict__ kf, unsigned short* __restrict__ vf,
    float* __restrict__ bqk)
{
  const int b = blockIdx.x;
  if (b < 2048) {
    const long i = (long)(b & 511) * 256 + threadIdx.x;
    if (b < 512)        cvt8(wq, Wb,            i);
    else if (b < 1024)  cvt8(wk, Wb + 1048576,  i);
    else if (b < 1536)  cvt8(wv, Wb + 2097152,  i);
    else                cvt8(wo, Wb + 3145728,  i);
  } else if (b < 6144) {
    cvt8(query, qf, (long)(b - 2048) * 256 + threadIdx.x);
  } else if (b < 10240) {
    cvt8(key_,  kf, (long)(b - 6144) * 256 + threadIdx.x);
  } else if (b < 10248) {
    const int t = (b - 10240) * 256 + threadIdx.x;
    if (t < 1024) bqk[t] = bq[t];
    else          bqk[t] = bk[t - 1024];
  } else {
    cvt8(value, vf, (long)(b - 10248) * 256 + threadIdx.x);
  }
}

__global__ __launch_bounds__(256) void cvt_f32_bf16(
    const float* __restrict__ in, unsigned short* __restrict__ out, int n8)
{
  const int i = blockIdx.x * 256 + threadIdx.x;
  if (i >= n8) return;
  cvt8(in, out, i);
}

// ---------------------------------------------------------------------------
__global__ __launch_bounds__(256) void softmax_inplace(unsigned short* __restrict__ P) {
  const long row = blockIdx.x;
  unsigned short* pr = P + row * 2048;
  const int tid = threadIdx.x;

  u32x4 raw = *(const u32x4*)&pr[tid * 8];
  float s[8];
  #pragma unroll
  for (int i = 0; i < 4; ++i) {
    unsigned int u = raw[i];
    s[2 * i]     = __builtin_bit_cast(float, u << 16);
    s[2 * i + 1] = __builtin_bit_cast(float, u & 0xFFFF0000u);
  }
  float m = s[0];
  #pragma unroll
  for (int i = 1; i < 8; ++i) m = fmaxf(m, s[i]);
  #pragma unroll
  for (int off = 32; off >= 1; off >>= 1) m = fmaxf(m, __shfl_xor(m, off));

  __shared__ float redm[4], reds[4];
  const int wid = tid >> 6, lane = tid & 63;
  if (lane == 0) redm[wid] = m;
  __syncthreads();
  m = fmaxf(fmaxf(redm[0], redm[1]), fmaxf(redm[2], redm[3]));

  float e[8], sum = 0.f;
  #pragma unroll
  for (int i = 0; i < 8; ++i) { e[i] = __expf(s[i] - m); sum += e[i]; }
  #pragma unroll
  for (int off = 32; off >= 1; off >>= 1) sum += __shfl_xor(sum, off);
  if (lane == 0) reds[wid] = sum;
  __syncthreads();
  sum = reds[0] + reds[1] + reds[2] + reds[3];
  const float inv = 1.0f / sum;

  u32x4 outw;
  #pragma unroll
  for (int i = 0; i < 4; ++i) outw[i] = pack2(e[2 * i] * inv, e[2 * i + 1] * inv);
  *(u32x4*)&pr[tid * 8] = outw;
}

// ---------------------------------------------------------------------------
extern "C" void kernel_launch(void* const* d_in, const int* in_sizes, int n_in,
                              void* d_out, int out_size, void* d_ws, size_t ws_size,
                              hipStream_t stream) {
  const float* query = (const float*)d_in[0];
  const float* key_  = (const float*)d_in[1];
  const float* value = (const float*)d_in[2];
  const float* Wq    = (const float*)d_in[3];
  const float* bq    = (const float*)d_in[4];
  const float* Wk    = (const float*)d_in[5];
  const float* bk    = (const float*)d_in[6];
  const float* Wv    = (const float*)d_in[7];
  const float* bv    = (const float*)d_in[8];
  const float* Wo    = (const float*)d_in[9];
  const float* bo    = (const float*)d_in[10];

  unsigned short* ws = (unsigned short*)d_ws;
  unsigned short* qf = ws;                        // [8192][1024] -> P lower
  unsigned short* kf = ws + 8388608;              // [8192][1024] -> P upper
  unsigned short* P  = ws;                        // [4][2048][2048]
  unsigned short* q  = ws + 16777216;             // [2][8.4M] q,k -> later o (fb)
  unsigned short* v  = ws + 33554432;             // [8192][1024] (par) / vT (fb)
  unsigned short* Wb = ws + 41943040;             // 4 x [1024][1024] bf16
  float*          bqk= (float*)(ws + 46137344);   // [2][1024] fp32
  unsigned short* o  = q;                         // fallback only

  const bool par = ws_size >= (size_t)(46141440 + 8388608) * 2;
  unsigned short* vf  = par ? (ws + 46141440) : ws;
  unsigned short* W2T = ws + 46141440;            // reuses dead vf (par only)

  const dim3 blk(256), blk8(512);

  // 0: all prologue conversions + bias copy in ONE dispatch
  mega_cvt3<<<dim3(par ? 14344 : 10248), blk, 0, stream>>>(
      Wq, Wk, Wv, Wo, query, key_, value, bq, bk, Wb, qf, kf, vf, bqk);

  if (par) {
    // 1: qkproj || vproj (independent)
    dual_qk_v<<<dim3(512), blk8, 0, stream>>>(qf, Wb, q, bqk,
                                              vf, Wb + 2097152, v, bv);
    // 2: scores || W2T = Wo @ v^T (independent; W2T overwrites dead vf)
    dual_sc_w2<<<dim3(512), blk8, 0, stream>>>(q, q + 8388608, P,
                                               Wb + 3145728, v, W2T);
    // 3: softmax rows in place (8192 rows x 2048)
    softmax_inplace<<<dim3(8192), blk, 0, stream>>>(P);
    // 4: out = P @ W2T^T + bo (fp32). M=2048, N=1024, K=2048, z=4.
    gemm8<1><<<dim3(8, 8, 4), blk8, 0, stream>>>(P, W2T, d_out,
        2048, 2048, 8192, 1024, 4194304L, 2048L, 2097152L, 0L, 1.0f, bo, 1);
  } else {
    // fallback: R16 exact serial path
    gemm256<0><<<dim3(4, 32, 2), blk8, 0, stream>>>(qf, Wb, q,
        1024, 1024, 1024, 1024, 8388608L, 1048576L, 8388608L, 1024L, 1.0f, bqk, 1);
    cvt_f32_bf16<<<dim3(4096), blk, 0, stream>>>(value, vf, 1048576);
    gemm8<0><<<dim3(64, 4, 1), blk8, 0, stream>>>(Wb + 2097152, vf, v,
        1024, 1024, 1024, 8192, 0L, 0L, 0L, 0L, 1.0f, bv, 2);
    gemm256<0><<<dim3(8, 8, 4), blk8, 0, stream>>>(q, q + 8388608, P,
        1024, 1024, 1024, 2048, 2097152L, 2097152L, 4194304L, 0L, 0.03125f, nullptr, 0);
    softmax_inplace<<<dim3(8192), blk, 0, stream>>>(P);
    gemm8<0><<<dim3(8, 8, 4), blk8, 0, stream>>>(P, v, o,
        2048, 2048, 8192, 1024, 4194304L, 2048L, 2097152L, 0L, 1.0f, nullptr, 0);
    gemm8<1><<<dim3(8, 32, 1), blk8, 0, stream>>>(o, Wb + 3145728, d_out,
        1024, 1024, 1024, 1024, 0L, 0L, 0L, 0L, 1.0f, bo, 1);
  }
}